// Round 10
// baseline (458.130 us; speedup 1.0000x reference)
//
#include <hip/hip_runtime.h>
#include <math.h>

#define BB 8
#define MTOK 768
#define NTOK 128
#define LTOK 64
#define TT 960          // MTOK+NTOK+LTOK
#define BT 7680         // BB*TT
#define DD 256
#define HH 8
#define HD 32
#define KNN 32
#define FFD 1024
#define NLAYERS 4
#define SCALE_ATT 0.17677669529663687f  // 1/sqrt(32)

typedef __attribute__((ext_vector_type(8))) short bfrag_t;   // 8 bf16 (4 VGPRs)
typedef __attribute__((ext_vector_type(4))) float accfrag_t; // 4 fp32 acc

__device__ __forceinline__ float b2f(unsigned short u) {
  union { unsigned int i; float f; } c; c.i = ((unsigned int)u) << 16; return c.f;
}
__device__ __forceinline__ unsigned short f2b(float f) {
  union { float f; unsigned int i; } c; c.f = f;
  return (unsigned short)((c.i + 0x7fffu + ((c.i >> 16) & 1u)) >> 16);
}
__device__ __forceinline__ float load_elem(const void* p, size_t i, int f) {
  return f ? b2f(((const unsigned short*)p)[i]) : ((const float*)p)[i];
}
// fragment-packed layout: element (row,k[col]) of [R x K] ->
//   ((row/16)*NKS + k/32)*512 + (((k>>3)&3)*16 + row%16)*8 + k%8
__device__ __forceinline__ size_t pk_addr(int row, int col, int nks) {
  return ((size_t)((row >> 4) * nks + (col >> 5)) << 9)
       + (size_t)(((((col >> 3) & 3) << 4) + (row & 15)) * 8 + (col & 7));
}
// scene->XCD swizzle
__device__ __forceinline__ int swiz_tok(int blk) { return (blk & 7) * TT + (blk >> 3); }

// ---------------- positions + params -> fp32 (with inline dtype detect) ----------------
#define FB_BQ 0
#define FB_BK 1024
#define FB_BV 2048
#define FB_BO 3072
#define FB_B1 4096
#define FB_B2 8192
#define FB_LN1S 9216
#define FB_LN1B 10240
#define FB_LN2S 11264
#define FB_LN2B 12288
#define FB_TOTAL 13312
struct ParamSrc { const void* p[13]; };
__global__ __launch_bounds__(256)
void conv_misc_kernel(ParamSrc ps, const void* tok, int* flagout,
                      float* __restrict__ dst, float* __restrict__ posf) {
  __shared__ int cnt;
  if (threadIdx.x == 0) cnt = 0;
  __syncthreads();
  const unsigned short* u = (const unsigned short*)tok;
  int ok = 0;
  for (int i = threadIdx.x; i < 1024; i += 256) {
    int e = (u[i] >> 7) & 0xFF;
    if (e >= 100 && e <= 140) ok++;
  }
  atomicAdd(&cnt, ok);
  __syncthreads();
  int f = (cnt >= 922) ? 1 : 0;
  if (blockIdx.x == 0 && threadIdx.x == 0) *flagout = f;
  if (blockIdx.x < BB) {
    int b = blockIdx.x;
    for (int t = threadIdx.x; t < TT * 2; t += 256) {
      int tok2 = t >> 1, c = t & 1;
      const void* p; size_t idx;
      if (tok2 < MTOK)             { p = ps.p[10]; idx = (size_t)(b * MTOK + tok2) * 2 + c; }
      else if (tok2 < MTOK + NTOK) { p = ps.p[11]; idx = (size_t)(b * NTOK + tok2 - MTOK) * 2 + c; }
      else                         { p = ps.p[12]; idx = (size_t)(b * LTOK + tok2 - MTOK - NTOK) * 2 + c; }
      posf[((size_t)b * TT + tok2) * 2 + c] = load_elem(p, idx, f);
    }
    return;
  }
  int i = (blockIdx.x - BB) * 256 + threadIdx.x;
  if (i >= FB_TOTAL) return;
  int src; size_t off;
  if (i < 4096)      { src = i >> 10;              off = i & 1023; }
  else if (i < 8192) { src = 4;                    off = i - 4096; }
  else               { src = 5 + ((i - 8192) >> 10); off = (i - 8192) & 1023; }
  dst[i] = load_elem(ps.p[src], off, f);
}

// ---------------- KNN helpers ----------------
__device__ __forceinline__ unsigned long long shfl_xor_u64(unsigned long long v, int m) {
  unsigned lo = (unsigned)v, hi = (unsigned)(v >> 32);
  lo = (unsigned)__shfl_xor((int)lo, m);
  hi = (unsigned)__shfl_xor((int)hi, m);
  return ((unsigned long long)hi << 32) | (unsigned long long)lo;
}
__device__ __forceinline__ unsigned long long shfl_u64(unsigned long long v, int srcLane) {
  unsigned lo = (unsigned)v, hi = (unsigned)(v >> 32);
  lo = (unsigned)__shfl((int)lo, srcLane);
  hi = (unsigned)__shfl((int)hi, srcLane);
  return ((unsigned long long)hi << 32) | (unsigned long long)lo;
}
__device__ __forceinline__ unsigned long long bitonic64(unsigned long long key, int lane) {
#pragma unroll
  for (int kk = 2; kk <= 64; kk <<= 1) {
#pragma unroll
    for (int j = kk >> 1; j > 0; j >>= 1) {
      unsigned long long other = shfl_xor_u64(key, j);
      bool small_ = (lane & j) == 0;
      bool dir = (lane & kk) == 0;
      bool keep = ((key < other) == (small_ == dir));
      key = keep ? key : other;
    }
  }
  return key;
}

// ---------------- mega setup: packW (coalesced) + prep + knn in one dispatch ----------------
// grid = 12288 (packW) + 7680 (prep) + 1920 (knn) = 21888
struct PackSrc { const void* s[6]; };
__global__ __launch_bounds__(256)
void mega_kernel(PackSrc w, const void* mt, const void* at, const void* lt,
                 const float* __restrict__ posf, const int* __restrict__ flag,
                 unsigned short* __restrict__ Wqkvpk, unsigned short* __restrict__ Wopk,
                 unsigned short* __restrict__ W1pk, unsigned short* __restrict__ W2pk,
                 unsigned short* __restrict__ pe_b, float* __restrict__ out_f,
                 unsigned short* __restrict__ pk1, unsigned short* __restrict__ qkpk,
                 int* __restrict__ idx_out) {
  __shared__ float sx[TT], sy[TT];
  __shared__ unsigned long long cbuf[4][64];
  int bid = blockIdx.x;
  if (bid < 12288) {
    // ---- packW: source-linear enumeration -> coalesced reads, local scatter writes
    int f = *flag;
    int id = bid * 256 + threadIdx.x;
    if (id < 786432) {                  // Wq,Wk,Wv (K=256,N=256)
      int layer = id / 196608, rest = id % 196608;
      int sel = rest >> 16, e = rest & 65535;
      int k = e >> 8, col = e & 255;
      const void* src = w.s[sel];
      size_t si = (size_t)layer * 65536 + e;
      Wqkvpk[(size_t)layer * 196608 + (size_t)sel * 65536 + pk_addr(col, k, 8)] =
          f ? ((const unsigned short*)src)[si] : f2b(((const float*)src)[si]);
    } else if (id < 1048576) {          // Wo (K=256,N=256)
      int off = id - 786432, layer = off >> 16, e = off & 65535;
      int k = e >> 8, col = e & 255;
      size_t si = (size_t)layer * 65536 + e;
      Wopk[(size_t)layer * 65536 + pk_addr(col, k, 8)] =
          f ? ((const unsigned short*)w.s[3])[si] : f2b(((const float*)w.s[3])[si]);
    } else if (id < 2097152) {          // W1 (K=256,N=1024)
      int off = id - 1048576, layer = off >> 18, e = off & 262143;
      int k = e >> 10, col = e & 1023;
      size_t si = (size_t)layer * 262144 + e;
      W1pk[(size_t)layer * 262144 + pk_addr(col, k, 8)] =
          f ? ((const unsigned short*)w.s[4])[si] : f2b(((const float*)w.s[4])[si]);
    } else {                            // W2 (K=1024,N=256)
      int off = id - 2097152, layer = off >> 18, e = off & 262143;
      int k = e >> 8, col = e & 255;
      size_t si = (size_t)layer * 262144 + e;
      W2pk[(size_t)layer * 262144 + pk_addr(col, k, 32)] =
          f ? ((const unsigned short*)w.s[5])[si] : f2b(((const float*)w.s[5])[si]);
    }
    return;
  }
  if (bid < 19968) {
    // ---- prep: positional embedding + stream init
    int n = swiz_tok(bid - 12288), d = threadIdx.x;
    int b = n / TT, t = n - b * TT;
    int f = *flag;
    const void* src; size_t si;
    if (t < MTOK)              { src = mt; si = (size_t)(b * MTOK + t) * DD + d; }
    else if (t < MTOK + NTOK)  { src = at; si = (size_t)(b * NTOK + (t - MTOK)) * DD + d; }
    else                       { src = lt; si = (size_t)(b * LTOK + (t - MTOK - NTOK)) * DD + d; }
    float x = load_elem(src, si, f);
    float px = posf[((size_t)b * TT + t) * 2 + 0];
    float py = posf[((size_t)b * TT + t) * 2 + 1];
    float coord = (d < 128) ? py : px;
    int j = d & 127;
    float expo = (float)(2 * (j >> 1)) / 128.0f;
    float dim_t = powf(10000.0f, expo);
    float e = coord * 6.283185307179586f / dim_t;
    float p = (j & 1) ? cosf(e) : sinf(e);
    size_t o = (size_t)n * DD + d;
    pe_b[o] = f2b(p);
    out_f[o] = x;
    size_t pa = pk_addr(n, d, 8);
    pk1[pa] = f2b(x);
    qkpk[pa] = f2b(x + p);
    return;
  }
  // ---- knn: threshold-prune + bitonic top-32 (exact)
  int kb = bid - 19968;
  int b = kb & 7;
  int qbase = (kb >> 3) * 4;
  for (int t = threadIdx.x; t < TT; t += 256) {
    sx[t] = posf[((size_t)b * TT + t) * 2 + 0];
    sy[t] = posf[((size_t)b * TT + t) * 2 + 1];
  }
  __syncthreads();
  int wave = threadIdx.x >> 6, lane = threadIdx.x & 63;
  int t = qbase + wave;
  float qx = sx[t], qy = sy[t];

  unsigned long long k[15];
#pragma unroll
  for (int c = 0; c < 15; c++) {
    int j = c * 64 + lane;
    float dx = qx - sx[j], dy = qy - sy[j];
    float d2 = __fadd_rn(__fmul_rn(dx, dx), __fmul_rn(dy, dy));
    k[c] = ((unsigned long long)__float_as_uint(d2) << 32) | (unsigned)j;
  }
  unsigned long long lm = k[0];
#pragma unroll
  for (int c = 1; c < 15; c++) lm = (k[c] < lm) ? k[c] : lm;

  unsigned long long sm = bitonic64(lm, lane);
  unsigned long long thr = shfl_u64(sm, 31);

  int c_l = 0;
#pragma unroll
  for (int c = 0; c < 15; c++) c_l += (k[c] <= thr) ? 1 : 0;
  int inc = c_l;
#pragma unroll
  for (int o = 1; o < 64; o <<= 1) {
    int tt = __shfl_up(inc, o);
    inc += (lane >= o) ? tt : 0;
  }
  int total = __shfl(inc, 63);
  int pos = inc - c_l;

  if (total <= 64) {
    unsigned long long* wb = cbuf[wave];
#pragma unroll
    for (int c = 0; c < 15; c++) {
      if (k[c] <= thr) { wb[pos] = k[c]; pos++; }
    }
    unsigned long long cand = (lane < total) ? wb[lane] : ~0ull;
    cand = bitonic64(cand, lane);
    if (lane < KNN)
      idx_out[((size_t)(b * TT + t)) * KNN + lane] = b * TT + (int)(cand & 0xFFFFFFFFu);
  } else {
    unsigned res = 0;
    for (int i = 0; i < KNN; i++) {
      unsigned long long m = k[0];
#pragma unroll
      for (int c = 1; c < 15; c++) m = (k[c] < m) ? k[c] : m;
#pragma unroll
      for (int o = 32; o > 0; o >>= 1) {
        unsigned long long om = shfl_xor_u64(m, o);
        m = (om < m) ? om : m;
      }
      if (lane == i) res = (unsigned)(m & 0xFFFFFFFFu);
      int owner = (int)(m & 63u), ch = (int)(((unsigned)(m & 0xFFFFFFFFu)) >> 6);
      if (lane == owner) {
#pragma unroll
        for (int c = 0; c < 15; c++) if (c == ch) k[c] = ~0ull;
      }
    }
    if (lane < KNN)
      idx_out[((size_t)(b * TT + t)) * KNN + lane] = b * TT + (int)res;
  }
}

// ---------------- wave GEMM: 16 rows x NT*16 cols ----------------
template<int NKS, int NT>
__device__ __forceinline__ void wavegemm(const unsigned short* __restrict__ Apk,
                                         const unsigned short* __restrict__ Bpk,
                                         int rb, int cb0, accfrag_t (&acc)[NT]) {
  const int lane = threadIdx.x & 63;
  accfrag_t z = {0.f, 0.f, 0.f, 0.f};
#pragma unroll
  for (int nt = 0; nt < NT; nt++) acc[nt] = z;
  const unsigned short* ap = Apk + ((size_t)rb * NKS * 512 + lane * 8);
  const unsigned short* bp = Bpk + ((size_t)cb0 * NKS * 512 + lane * 8);
#pragma unroll 4
  for (int ks = 0; ks < NKS; ks++) {
    bfrag_t a = *(const bfrag_t*)(ap + ks * 512);
#pragma unroll
    for (int nt = 0; nt < NT; nt++) {
      bfrag_t b = *(const bfrag_t*)(bp + (size_t)(nt * NKS + ks) * 512);
      acc[nt] = __builtin_amdgcn_mfma_f32_16x16x32_bf16(a, b, acc[nt], 0, 0, 0);
    }
  }
}

// ---------------- QKV GEMM (layer 0 only): grid 1440 ----------------
__global__ __launch_bounds__(256)
void qkv_kernel(const unsigned short* __restrict__ qkpk,
                const unsigned short* __restrict__ outpk,
                const unsigned short* __restrict__ Wl,
                const float* __restrict__ pb, int l,
                unsigned short* __restrict__ QKV) {
  int scene = blockIdx.x & 7, r = blockIdx.x >> 3;
  int rbg = r % 15, cgall = r / 15;           // cgall 0..11
  int wave = threadIdx.x >> 6, lane = threadIdx.x & 63;
  int rb = scene * 60 + rbg * 4 + wave;
  int sel = cgall >> 2, cg = cgall & 3;
  const unsigned short* A = (sel < 2) ? qkpk : outpk;
  const unsigned short* B = Wl + sel * 65536;
  const float* bias = pb + sel * 1024 + l * 256;
  accfrag_t acc[4];
  wavegemm<8,4>(A, B, rb, cg * 4, acc);
  int l16 = lane & 15, lq = lane >> 4;
  unsigned short* C = QKV + (size_t)sel * BT * DD;
#pragma unroll
  for (int nt = 0; nt < 4; nt++) {
    int col = cg * 64 + nt * 16 + l16;
    float bv = bias[col];
#pragma unroll
    for (int r4 = 0; r4 < 4; r4++) {
      int row = rb * 16 + lq * 4 + r4;
      C[(size_t)row * DD + col] = f2b(acc[nt][r4] + bv);
    }
  }
}

// ---------------- fused layer: attn -> Wo+resid+LN1 -> FFN1 -> FFN2+resid+LN2 [-> next QKV] ----
// grid 480 x 256 threads (4 waves). One block = 16 tokens (one row-block) x all 256 cols.
// Phase 0: WAVE-PARALLEL attention (each wave one token, 4 groups, zero inner barriers):
//   lanes (half,j) compute QK dots with vectorized loads; softmax via width-32 shfl trees
//   (identical reduction order to reference); att crosses the lane-remap through a 33-padded
//   wave-private LDS buffer; PV gathers V coalesced, j-order identical. Output -> apk (LDS).
// Phases 1-4 identical to the proven R5/R8 structure. QKVin/QKVout ping-pong (no race).
template<bool LAST>
__global__ __launch_bounds__(256)
void layer_kernel(const unsigned short* __restrict__ QKVin,
                  const int* __restrict__ idx,
                  const unsigned short* __restrict__ Wo,
                  const unsigned short* __restrict__ W1,
                  const unsigned short* __restrict__ W2,
                  const unsigned short* __restrict__ Wn,   // next-layer Wqkv (packed)
                  const float* __restrict__ bo,
                  const float* __restrict__ b1,
                  const float* __restrict__ b2,
                  const float* __restrict__ pb, int ln,    // bias base, next layer idx
                  float* __restrict__ yf,                  // residual stream (f32)
                  const unsigned short* __restrict__ pe_b,
                  const float* __restrict__ g1, const float* __restrict__ t1,
                  const float* __restrict__ g2, const float* __restrict__ t2,
                  unsigned short* __restrict__ QKVout,
                  void* __restrict__ dout, const int* __restrict__ flag) {
  // uA: phase 0 uses first ~4.3 KB as attW scratch; later xls (8 KB) + hls (32 KB).
  __shared__ char uA[40960];
  __shared__ unsigned short apk[4096];       // 16r x 256c packed attn output, 8 KB
  __shared__ int nbAll[16][KNN];
  __shared__ float ps1[4][16], ps2[4][16];
  unsigned short* xls = (unsigned short*)uA;            // 8 KB (16r x 256k, NKS=8)
  unsigned short* hls = (unsigned short*)(uA + 8192);   // 32 KB (16r x 1024k, NKS=32)

  int scene = blockIdx.x & 7, rbs = blockIdx.x >> 3;   // rbs 0..59
  int wave = threadIdx.x >> 6, lane = threadIdx.x & 63;
  int rb = scene * 60 + rbs;
  int n0 = rb * 16;                                    // first global token row
  int l16 = lane & 15, lq = lane >> 4;
  int tid = threadIdx.x;

  // ---- phase 0: wave-parallel attention
  const unsigned short* Qp = QKVin;
  const unsigned short* Kp = QKVin + (size_t)BT * DD;
  const unsigned short* Vp = QKVin + 2 * (size_t)BT * DD;
  for (int i = tid; i < 16 * KNN; i += 256)
    nbAll[i >> 5][i & 31] = idx[(size_t)(n0 + (i >> 5)) * KNN + (i & 31)];
  __syncthreads();
  {
    float* attW = (float*)uA + wave * (8 * 33 + 4);   // 33-padded, wave-private
    int j32 = lane & 31, half = lane >> 5;
    int h2 = lane >> 3, d0 = (lane & 7) * 4;
    for (int g = 0; g < 4; g++) {
      int t16 = g * 4 + wave;
      int n = n0 + t16;
      int nbj = nbAll[t16][j32];
      const bfrag_t* kr = (const bfrag_t*)(Kp + (size_t)nbj * DD + half * 128);
      const bfrag_t* qr = (const bfrag_t*)(Qp + (size_t)n * DD + half * 128);
      float att4[4];
#pragma unroll
      for (int h = 0; h < 4; h++) {
        bfrag_t q0 = qr[h * 4 + 0], q1 = qr[h * 4 + 1], q2 = qr[h * 4 + 2], q3 = qr[h * 4 + 3];
        bfrag_t k0 = kr[h * 4 + 0], k1 = kr[h * 4 + 1], k2 = kr[h * 4 + 2], k3 = kr[h * 4 + 3];
        float dot = 0.0f;
#pragma unroll
        for (int e = 0; e < 8; e++) dot += b2f((unsigned short)q0[e]) * b2f((unsigned short)k0[e]);
#pragma unroll
        for (int e = 0; e < 8; e++) dot += b2f((unsigned short)q1[e]) * b2f((unsigned short)k1[e]);
#pragma unroll
        for (int e = 0; e < 8; e++) dot += b2f((unsigned short)q2[e]) * b2f((unsigned short)k2[e]);
#pragma unroll
        for (int e = 0; e < 8; e++) dot += b2f((unsigned short)q3[e]) * b2f((unsigned short)k3[e]);
        float sc = dot * SCALE_ATT;
        float mx = sc;
#pragma unroll
        for (int o = 16; o > 0; o >>= 1) mx = fmaxf(mx, __shfl_xor(mx, o, 32));
        float ex = expf(sc - mx);
        float sm = ex;
#pragma unroll
        for (int o = 16; o > 0; o >>= 1) sm += __shfl_xor(sm, o, 32);
        att4[h] = ex / sm;
      }
#pragma unroll
      for (int h = 0; h < 4; h++)
        attW[(half * 4 + h) * 33 + j32] = att4[h];
      // PV: lane remap (h2, d0); j-order identical to reference
      float o4[4] = {0.f, 0.f, 0.f, 0.f};
      for (int j = 0; j < KNN; j++) {
        float a = attW[h2 * 33 + j];
        int nv = nbAll[t16][j];
        union { unsigned int u[2]; unsigned short s[4]; } vv;
        *(uint2*)vv.u = *(const uint2*)(Vp + (size_t)nv * DD + h2 * HD + d0);
#pragma unroll
        for (int e = 0; e < 4; e++) o4[e] += a * b2f(vv.s[e]);
      }
      int col = h2 * HD + d0;
      unsigned short* ap = apk + pk_addr(t16, col, 8);
      ap[0] = f2b(o4[0]); ap[1] = f2b(o4[1]); ap[2] = f2b(o4[2]); ap[3] = f2b(o4[3]);
    }
  }
  __syncthreads();   // attW dead; apk complete; uA free for xls/hls

  // ---- residual prefetch (issue loads before the GEMM; consumed in LN1 epilogue)
  float resv[4][4];
#pragma unroll
  for (int nt = 0; nt < 4; nt++) {
    int col = wave * 64 + nt * 16 + l16;
#pragma unroll
    for (int r4 = 0; r4 < 4; r4++) {
      int row = rb * 16 + lq * 4 + r4;
      resv[nt][r4] = yf[(size_t)row * DD + col];
    }
  }

  // ---- phase 1: Wo GEMM (A from apk LDS) + bias + residual + LN1 -> y (regs) + xls
  accfrag_t acc[4];
  wavegemm<8,4>(apk, Wo, 0, wave * 4, acc);
  float y[4][4];
  float s[4] = {0.f, 0.f, 0.f, 0.f}, s2[4] = {0.f, 0.f, 0.f, 0.f};
#pragma unroll
  for (int nt = 0; nt < 4; nt++) {
    int col = wave * 64 + nt * 16 + l16;
    float bv = bo[col];
#pragma unroll
    for (int r4 = 0; r4 < 4; r4++) {
      float x = acc[nt][r4] + bv + resv[nt][r4];
      y[nt][r4] = x; s[r4] += x; s2[r4] += x * x;
    }
  }
#pragma unroll
  for (int o = 1; o < 16; o <<= 1) {
#pragma unroll
    for (int r4 = 0; r4 < 4; r4++) { s[r4] += __shfl_xor(s[r4], o); s2[r4] += __shfl_xor(s2[r4], o); }
  }
  if (l16 == 0) {
#pragma unroll
    for (int r4 = 0; r4 < 4; r4++) { ps1[wave][lq * 4 + r4] = s[r4]; ps2[wave][lq * 4 + r4] = s2[r4]; }
  }
  __syncthreads();
#pragma unroll
  for (int r4 = 0; r4 < 4; r4++) {
    int r16 = lq * 4 + r4;
    float ts  = ps1[0][r16] + ps1[1][r16] + ps1[2][r16] + ps1[3][r16];
    float ts2 = ps2[0][r16] + ps2[1][r16] + ps2[2][r16] + ps2[3][r16];
    float mu = ts * (1.0f / 256.0f);
    float var = ts2 * (1.0f / 256.0f) - mu * mu;
    float rstd = 1.0f / sqrtf(fmaxf(var, 0.f) + 1e-5f);
#pragma unroll
    for (int nt = 0; nt < 4; nt++) {
      int col = wave * 64 + nt * 16 + l16;
      float v = (y[nt][r4] - mu) * rstd * g1[col] + t1[col];
      y[nt][r4] = v;
      xls[pk_addr(r16, col, 8)] = f2b(v);
    }
  }
  __syncthreads();

  // ---- phase 2: FFN1 (xls @ W1 + b1, ReLU) -> hls (LDS packed)
#pragma unroll
  for (int i = 0; i < 4; i++) {
    int cg = wave * 4 + i;
    accfrag_t a2[4];
    wavegemm<8,4>(xls, W1, 0, cg * 4, a2);
#pragma unroll
    for (int nt = 0; nt < 4; nt++) {
      int col = cg * 64 + nt * 16 + l16;
      float bv = b1[col];
#pragma unroll
      for (int r4 = 0; r4 < 4; r4++)
        hls[pk_addr(lq * 4 + r4, col, 32)] = f2b(fmaxf(a2[nt][r4] + bv, 0.0f));
    }
  }
  __syncthreads();

  // ---- phase 3: FFN2 (hls @ W2 + b2) + residual(y) + LN2
  accfrag_t a3[4];
  wavegemm<32,4>(hls, W2, 0, wave * 4, a3);
  float v2[4][4];
  float s3[4] = {0.f, 0.f, 0.f, 0.f}, s4[4] = {0.f, 0.f, 0.f, 0.f};
#pragma unroll
  for (int nt = 0; nt < 4; nt++) {
    int col = wave * 64 + nt * 16 + l16;
    float bv = b2[col];
#pragma unroll
    for (int r4 = 0; r4 < 4; r4++) {
      float x = a3[nt][r4] + bv + y[nt][r4];
      v2[nt][r4] = x; s3[r4] += x; s4[r4] += x * x;
    }
  }
#pragma unroll
  for (int o = 1; o < 16; o <<= 1) {
#pragma unroll
    for (int r4 = 0; r4 < 4; r4++) { s3[r4] += __shfl_xor(s3[r4], o); s4[r4] += __shfl_xor(s4[r4], o); }
  }
  if (l16 == 0) {
#pragma unroll
    for (int r4 = 0; r4 < 4; r4++) { ps1[wave][lq * 4 + r4] = s3[r4]; ps2[wave][lq * 4 + r4] = s4[r4]; }
  }
  __syncthreads();     // after this barrier all waves are done reading hls (phase-3 GEMM)
  unsigned short* qkls = hls;   // reuse first 8 KB of hls for packed (y+pe)
  int fl = LAST ? *flag : 0;
#pragma unroll
  for (int r4 = 0; r4 < 4; r4++) {
    int r16 = lq * 4 + r4;
    float ts  = ps1[0][r16] + ps1[1][r16] + ps1[2][r16] + ps1[3][r16];
    float ts2 = ps2[0][r16] + ps2[1][r16] + ps2[2][r16] + ps2[3][r16];
    float mu = ts * (1.0f / 256.0f);
    float var = ts2 * (1.0f / 256.0f) - mu * mu;
    float rstd = 1.0f / sqrtf(fmaxf(var, 0.f) + 1e-5f);
#pragma unroll
    for (int nt = 0; nt < 4; nt++) {
      int col = wave * 64 + nt * 16 + l16;
      float yv = (v2[nt][r4] - mu) * rstd * g2[col] + t2[col];
      int row = rb * 16 + r16;
      if (!LAST) {
        yf[(size_t)row * DD + col] = yv;           // residual for next layer
        float q = yv + b2f(pe_b[(size_t)row * DD + col]);
        xls[pk_addr(r16, col, 8)] = f2b(yv);       // out (for V projection)
        qkls[pk_addr(r16, col, 8)] = f2b(q);       // out+pe (for Q/K projection)
      } else {
        int t = rbs * 16 + r16;   // token within scene
        size_t o;
        if (t < MTOK)             o = (size_t)(scene * MTOK + t) * DD + col;
        else if (t < MTOK + NTOK) o = (size_t)BB * MTOK * DD + (size_t)(scene * NTOK + (t - MTOK)) * DD + col;
        else                      o = (size_t)BB * MTOK * DD + (size_t)BB * NTOK * DD
                                    + (size_t)(scene * LTOK + (t - MTOK - NTOK)) * DD + col;
        if (fl) ((unsigned short*)dout)[o] = f2b(yv);
        else    ((float*)dout)[o] = yv;
      }
    }
  }

  // ---- phase 4 (!LAST): next-layer QKV projection straight from LDS -> QKVout
  if (!LAST) {
    __syncthreads();
#pragma unroll
    for (int i = 0; i < 3; i++) {
      int cgall = wave * 3 + i;            // 12 tiles: Q(0-3) K(4-7) V(8-11)
      int sel = cgall >> 2, cg = cgall & 3;
      const unsigned short* A = (sel < 2) ? qkls : xls;
      accfrag_t a4[4];
      wavegemm<8,4>(A, Wn + sel * 65536, 0, cg * 4, a4);
      const float* bias = pb + sel * 1024 + ln * 256;
      unsigned short* C = QKVout + (size_t)sel * BT * DD;
#pragma unroll
      for (int nt = 0; nt < 4; nt++) {
        int col = cg * 64 + nt * 16 + l16;
        float bv = bias[col];
#pragma unroll
        for (int r4 = 0; r4 < 4; r4++) {
          int row = rb * 16 + lq * 4 + r4;
          C[(size_t)row * DD + col] = f2b(a4[nt][r4] + bv);
        }
      }
    }
  }
}

// ---------------- launcher ----------------
extern "C" void kernel_launch(void* const* d_in, const int* in_sizes, int n_in,
                              void* d_out, int out_size, void* d_ws, size_t ws_size,
                              hipStream_t stream) {
  const void* map_tok   = d_in[0];
  const void* agent_tok = d_in[1];
  const void* light_tok = d_in[2];
  const void* map_pos   = d_in[3];
  const void* agent_pos = d_in[4];
  const void* light_pos = d_in[5];
  const void* Wq  = d_in[9];
  const void* bq  = d_in[10];
  const void* Wk  = d_in[11];
  const void* bk  = d_in[12];
  const void* Wv  = d_in[13];
  const void* bv  = d_in[14];
  const void* Wo  = d_in[15];
  const void* bo  = d_in[16];
  const void* W1  = d_in[17];
  const void* b1  = d_in[18];
  const void* W2  = d_in[19];
  const void* b2  = d_in[20];
  const void* ln1s = d_in[21];
  const void* ln1b = d_in[22];
  const void* ln2s = d_in[23];
  const void* ln2b = d_in[24];

  size_t off = 0;
  char* base = (char*)d_ws;
  auto take = [&](size_t bytes) { char* p = base + off; off += (bytes + 255) & ~(size_t)255; return (void*)p; };
  int*   flag  = (int*)take(256);
  float* posf  = (float*)take((size_t)BT * 2 * 4);
  float* pbuf  = (float*)take((size_t)FB_TOTAL * 4);
  unsigned short* pe_b = (unsigned short*)take((size_t)BT * DD * 2);
  float* out_f = (float*)take((size_t)BT * DD * 4);   // residual stream (f32)
  unsigned short* pk1  = (unsigned short*)take((size_t)BT * DD * 2);  // layer-0 x packed
  unsigned short* qkpk = (unsigned short*)take((size_t)BT * DD * 2);  // layer-0 x+pe packed
  unsigned short* QKVa = (unsigned short*)take((size_t)3 * BT * DD * 2);
  unsigned short* QKVb = (unsigned short*)take((size_t)3 * BT * DD * 2);
  int* idxb = (int*)take((size_t)BT * KNN * 4);
  unsigned short* Wqkvpk = (unsigned short*)take((size_t)NLAYERS * 3 * DD * DD * 2);
  unsigned short* Wopk   = (unsigned short*)take((size_t)NLAYERS * DD * DD * 2);
  unsigned short* W1pk   = (unsigned short*)take((size_t)NLAYERS * DD * FFD * 2);
  unsigned short* W2pk   = (unsigned short*)take((size_t)NLAYERS * DD * FFD * 2);

  ParamSrc ps; ps.p[0]=bq; ps.p[1]=bk; ps.p[2]=bv; ps.p[3]=bo; ps.p[4]=b1;
  ps.p[5]=b2; ps.p[6]=ln1s; ps.p[7]=ln1b; ps.p[8]=ln2s; ps.p[9]=ln2b;
  ps.p[10]=map_pos; ps.p[11]=agent_pos; ps.p[12]=light_pos;
  conv_misc_kernel<<<BB + (FB_TOTAL + 255) / 256, 256, 0, stream>>>(ps, map_tok, flag, pbuf, posf);

  PackSrc pw; pw.s[0]=Wq; pw.s[1]=Wk; pw.s[2]=Wv; pw.s[3]=Wo; pw.s[4]=W1; pw.s[5]=W2;
  mega_kernel<<<21888, 256, 0, stream>>>(pw, map_tok, agent_tok, light_tok, posf, flag,
                                         Wqkvpk, Wopk, W1pk, W2pk,
                                         pe_b, out_f, pk1, qkpk, idxb);

  qkv_kernel<<<1440, 256, 0, stream>>>(qkpk, pk1, Wqkvpk, pbuf, 0, QKVa);

  for (int l = 0; l < NLAYERS; l++) {
    unsigned short* Qin  = (l & 1) ? QKVb : QKVa;
    unsigned short* Qout = (l & 1) ? QKVa : QKVb;
    if (l < NLAYERS - 1)
      layer_kernel<false><<<480, 256, 0, stream>>>(
          Qin, idxb,
          Wopk + (size_t)l * 65536, W1pk + (size_t)l * 262144, W2pk + (size_t)l * 262144,
          Wqkvpk + (size_t)(l + 1) * 196608,
          pbuf + FB_BO + l * 256, pbuf + FB_B1 + l * 1024, pbuf + FB_B2 + l * 256,
          pbuf, l + 1,
          out_f, pe_b,
          pbuf + FB_LN1S + l * 256, pbuf + FB_LN1B + l * 256,
          pbuf + FB_LN2S + l * 256, pbuf + FB_LN2B + l * 256,
          Qout, d_out, flag);
    else
      layer_kernel<true><<<480, 256, 0, stream>>>(
          Qin, idxb,
          Wopk + (size_t)l * 65536, W1pk + (size_t)l * 262144, W2pk + (size_t)l * 262144,
          Wqkvpk,
          pbuf + FB_BO + l * 256, pbuf + FB_B1 + l * 1024, pbuf + FB_B2 + l * 256,
          pbuf, 0,
          out_f, pe_b,
          pbuf + FB_LN1S + l * 256, pbuf + FB_LN1B + l * 256,
          pbuf + FB_LN2S + l * 256, pbuf + FB_LN2B + l * 256,
          Qout, d_out, flag);
  }
}

// Round 11
// 449.066 us; speedup vs baseline: 1.0202x; 1.0202x over previous
//
#include <hip/hip_runtime.h>
#include <math.h>

#define BB 8
#define MTOK 768
#define NTOK 128
#define LTOK 64
#define TT 960          // MTOK+NTOK+LTOK
#define BT 7680         // BB*TT
#define DD 256
#define HH 8
#define HD 32
#define KNN 32
#define FFD 1024
#define NLAYERS 4
#define SCALE_ATT 0.17677669529663687f  // 1/sqrt(32)

typedef __attribute__((ext_vector_type(8))) short bfrag_t;   // 8 bf16 (4 VGPRs)
typedef __attribute__((ext_vector_type(4))) float accfrag_t; // 4 fp32 acc

__device__ __forceinline__ float b2f(unsigned short u) {
  union { unsigned int i; float f; } c; c.i = ((unsigned int)u) << 16; return c.f;
}
__device__ __forceinline__ unsigned short f2b(float f) {
  union { float f; unsigned int i; } c; c.f = f;
  return (unsigned short)((c.i + 0x7fffu + ((c.i >> 16) & 1u)) >> 16);
}
__device__ __forceinline__ float load_elem(const void* p, size_t i, int f) {
  return f ? b2f(((const unsigned short*)p)[i]) : ((const float*)p)[i];
}
// fragment-packed layout: element (row,k[col]) of [R x K] ->
//   ((row/16)*NKS + k/32)*512 + (((k>>3)&3)*16 + row%16)*8 + k%8
__device__ __forceinline__ size_t pk_addr(int row, int col, int nks) {
  return ((size_t)((row >> 4) * nks + (col >> 5)) << 9)
       + (size_t)(((((col >> 3) & 3) << 4) + (row & 15)) * 8 + (col & 7));
}
// scene->XCD swizzle
__device__ __forceinline__ int swiz_tok(int blk) { return (blk & 7) * TT + (blk >> 3); }

#define FB_BQ 0
#define FB_BK 1024
#define FB_BV 2048
#define FB_BO 3072
#define FB_B1 4096
#define FB_B2 8192
#define FB_LN1S 9216
#define FB_LN1B 10240
#define FB_LN2S 11264
#define FB_LN2B 12288
#define FB_TOTAL 13312

// ---------------- KNN helpers ----------------
__device__ __forceinline__ unsigned long long shfl_xor_u64(unsigned long long v, int m) {
  unsigned lo = (unsigned)v, hi = (unsigned)(v >> 32);
  lo = (unsigned)__shfl_xor((int)lo, m);
  hi = (unsigned)__shfl_xor((int)hi, m);
  return ((unsigned long long)hi << 32) | (unsigned long long)lo;
}
__device__ __forceinline__ unsigned long long shfl_u64(unsigned long long v, int srcLane) {
  unsigned lo = (unsigned)v, hi = (unsigned)(v >> 32);
  lo = (unsigned)__shfl((int)lo, srcLane);
  hi = (unsigned)__shfl((int)hi, srcLane);
  return ((unsigned long long)hi << 32) | (unsigned long long)lo;
}
__device__ __forceinline__ unsigned long long bitonic64(unsigned long long key, int lane) {
#pragma unroll
  for (int kk = 2; kk <= 64; kk <<= 1) {
#pragma unroll
    for (int j = kk >> 1; j > 0; j >>= 1) {
      unsigned long long other = shfl_xor_u64(key, j);
      bool small_ = (lane & j) == 0;
      bool dir = (lane & kk) == 0;
      bool keep = ((key < other) == (small_ == dir));
      key = keep ? key : other;
    }
  }
  return key;
}

// ---------------- mega setup: packW + prep + knn + params, one dispatch ----------------
// grid = 12288 (packW) + 7680 (prep) + 1920 (knn) + 52 (pbuf) = 21940.
// Every block recomputes the dtype flag inline (1024-elem scan of map_tok, L2-cached);
// positions are loaded directly from source arrays (bit-identical to old posf path).
struct PackSrc { const void* s[6]; };
struct ParamSrc { const void* p[13]; };
__global__ __launch_bounds__(256)
void mega_kernel(PackSrc w, ParamSrc ps, const void* mt, const void* at, const void* lt,
                 int* __restrict__ flagout,
                 unsigned short* __restrict__ Wqkvpk, unsigned short* __restrict__ Wopk,
                 unsigned short* __restrict__ W1pk, unsigned short* __restrict__ W2pk,
                 unsigned short* __restrict__ pe_b, float* __restrict__ out_f,
                 unsigned short* __restrict__ pk1, unsigned short* __restrict__ qkpk,
                 int* __restrict__ idx_out, float* __restrict__ pbuf) {
  __shared__ float sx[TT], sy[TT];
  __shared__ unsigned long long cbuf[4][64];
  __shared__ int cnt;
  if (threadIdx.x == 0) cnt = 0;
  __syncthreads();
  {
    const unsigned short* u = (const unsigned short*)mt;
    int ok = 0;
    for (int i = threadIdx.x; i < 1024; i += 256) {
      int e = (u[i] >> 7) & 0xFF;
      if (e >= 100 && e <= 140) ok++;
    }
    atomicAdd(&cnt, ok);
  }
  __syncthreads();
  int f = (cnt >= 922) ? 1 : 0;
  int bid = blockIdx.x;
  if (bid == 0 && threadIdx.x == 0) *flagout = f;

  if (bid < 12288) {
    // ---- packW: source-linear enumeration -> coalesced reads, local scatter writes
    int id = bid * 256 + threadIdx.x;
    if (id < 786432) {                  // Wq,Wk,Wv (K=256,N=256)
      int layer = id / 196608, rest = id % 196608;
      int sel = rest >> 16, e = rest & 65535;
      int k = e >> 8, col = e & 255;
      const void* src = w.s[sel];
      size_t si = (size_t)layer * 65536 + e;
      Wqkvpk[(size_t)layer * 196608 + (size_t)sel * 65536 + pk_addr(col, k, 8)] =
          f ? ((const unsigned short*)src)[si] : f2b(((const float*)src)[si]);
    } else if (id < 1048576) {          // Wo (K=256,N=256)
      int off = id - 786432, layer = off >> 16, e = off & 65535;
      int k = e >> 8, col = e & 255;
      size_t si = (size_t)layer * 65536 + e;
      Wopk[(size_t)layer * 65536 + pk_addr(col, k, 8)] =
          f ? ((const unsigned short*)w.s[3])[si] : f2b(((const float*)w.s[3])[si]);
    } else if (id < 2097152) {          // W1 (K=256,N=1024)
      int off = id - 1048576, layer = off >> 18, e = off & 262143;
      int k = e >> 10, col = e & 1023;
      size_t si = (size_t)layer * 262144 + e;
      W1pk[(size_t)layer * 262144 + pk_addr(col, k, 8)] =
          f ? ((const unsigned short*)w.s[4])[si] : f2b(((const float*)w.s[4])[si]);
    } else {                            // W2 (K=1024,N=256)
      int off = id - 2097152, layer = off >> 18, e = off & 262143;
      int k = e >> 8, col = e & 255;
      size_t si = (size_t)layer * 262144 + e;
      W2pk[(size_t)layer * 262144 + pk_addr(col, k, 32)] =
          f ? ((const unsigned short*)w.s[5])[si] : f2b(((const float*)w.s[5])[si]);
    }
    return;
  }
  if (bid < 19968) {
    // ---- prep: positional embedding + stream init (positions loaded directly)
    int n = swiz_tok(bid - 12288), d = threadIdx.x;
    int b = n / TT, t = n - b * TT;
    const void* src; size_t si;
    const void* pp; size_t pi;
    if (t < MTOK)              { src = mt; si = (size_t)(b * MTOK + t) * DD + d;
                                 pp = ps.p[10]; pi = (size_t)(b * MTOK + t) * 2; }
    else if (t < MTOK + NTOK)  { src = at; si = (size_t)(b * NTOK + (t - MTOK)) * DD + d;
                                 pp = ps.p[11]; pi = (size_t)(b * NTOK + (t - MTOK)) * 2; }
    else                       { src = lt; si = (size_t)(b * LTOK + (t - MTOK - NTOK)) * DD + d;
                                 pp = ps.p[12]; pi = (size_t)(b * LTOK + (t - MTOK - NTOK)) * 2; }
    float x = load_elem(src, si, f);
    float px = load_elem(pp, pi + 0, f);
    float py = load_elem(pp, pi + 1, f);
    float coord = (d < 128) ? py : px;
    int j = d & 127;
    float expo = (float)(2 * (j >> 1)) / 128.0f;
    float dim_t = powf(10000.0f, expo);
    float e = coord * 6.283185307179586f / dim_t;
    float p = (j & 1) ? cosf(e) : sinf(e);
    size_t o = (size_t)n * DD + d;
    pe_b[o] = f2b(p);
    out_f[o] = x;
    size_t pa = pk_addr(n, d, 8);
    pk1[pa] = f2b(x);
    qkpk[pa] = f2b(x + p);
    return;
  }
  if (bid < 21888) {
    // ---- knn: threshold-prune + bitonic top-32 (exact); positions loaded directly
    int kb = bid - 19968;
    int b = kb & 7;
    int qbase = (kb >> 3) * 4;
    for (int t = threadIdx.x; t < TT; t += 256) {
      const void* pp; size_t pi;
      if (t < MTOK)             { pp = ps.p[10]; pi = (size_t)(b * MTOK + t) * 2; }
      else if (t < MTOK + NTOK) { pp = ps.p[11]; pi = (size_t)(b * NTOK + (t - MTOK)) * 2; }
      else                      { pp = ps.p[12]; pi = (size_t)(b * LTOK + (t - MTOK - NTOK)) * 2; }
      sx[t] = load_elem(pp, pi + 0, f);
      sy[t] = load_elem(pp, pi + 1, f);
    }
    __syncthreads();
    int wave = threadIdx.x >> 6, lane = threadIdx.x & 63;
    int t = qbase + wave;
    float qx = sx[t], qy = sy[t];

    unsigned long long k[15];
#pragma unroll
    for (int c = 0; c < 15; c++) {
      int j = c * 64 + lane;
      float dx = qx - sx[j], dy = qy - sy[j];
      float d2 = __fadd_rn(__fmul_rn(dx, dx), __fmul_rn(dy, dy));
      k[c] = ((unsigned long long)__float_as_uint(d2) << 32) | (unsigned)j;
    }
    unsigned long long lm = k[0];
#pragma unroll
    for (int c = 1; c < 15; c++) lm = (k[c] < lm) ? k[c] : lm;

    unsigned long long sm = bitonic64(lm, lane);
    unsigned long long thr = shfl_u64(sm, 31);

    int c_l = 0;
#pragma unroll
    for (int c = 0; c < 15; c++) c_l += (k[c] <= thr) ? 1 : 0;
    int inc = c_l;
#pragma unroll
    for (int o = 1; o < 64; o <<= 1) {
      int tt = __shfl_up(inc, o);
      inc += (lane >= o) ? tt : 0;
    }
    int total = __shfl(inc, 63);
    int pos = inc - c_l;

    if (total <= 64) {
      unsigned long long* wb = cbuf[wave];
#pragma unroll
      for (int c = 0; c < 15; c++) {
        if (k[c] <= thr) { wb[pos] = k[c]; pos++; }
      }
      unsigned long long cand = (lane < total) ? wb[lane] : ~0ull;
      cand = bitonic64(cand, lane);
      if (lane < KNN)
        idx_out[((size_t)(b * TT + t)) * KNN + lane] = b * TT + (int)(cand & 0xFFFFFFFFu);
    } else {
      unsigned res = 0;
      for (int i = 0; i < KNN; i++) {
        unsigned long long m = k[0];
#pragma unroll
        for (int c = 1; c < 15; c++) m = (k[c] < m) ? k[c] : m;
#pragma unroll
        for (int o = 32; o > 0; o >>= 1) {
          unsigned long long om = shfl_xor_u64(m, o);
          m = (om < m) ? om : m;
        }
        if (lane == i) res = (unsigned)(m & 0xFFFFFFFFu);
        int owner = (int)(m & 63u), ch = (int)(((unsigned)(m & 0xFFFFFFFFu)) >> 6);
        if (lane == owner) {
#pragma unroll
          for (int c = 0; c < 15; c++) if (c == ch) k[c] = ~0ull;
        }
      }
      if (lane < KNN)
        idx_out[((size_t)(b * TT + t)) * KNN + lane] = b * TT + (int)res;
    }
    return;
  }
  // ---- pbuf: biases + LN params -> fp32
  int i = (bid - 21888) * 256 + threadIdx.x;
  if (i >= FB_TOTAL) return;
  int src; size_t off;
  if (i < 4096)      { src = i >> 10;              off = i & 1023; }
  else if (i < 8192) { src = 4;                    off = i - 4096; }
  else               { src = 5 + ((i - 8192) >> 10); off = (i - 8192) & 1023; }
  pbuf[i] = load_elem(ps.p[src], off, f);
}

// ---------------- wave GEMM: 16 rows x NT*16 cols ----------------
template<int NKS, int NT>
__device__ __forceinline__ void wavegemm(const unsigned short* __restrict__ Apk,
                                         const unsigned short* __restrict__ Bpk,
                                         int rb, int cb0, accfrag_t (&acc)[NT]) {
  const int lane = threadIdx.x & 63;
  accfrag_t z = {0.f, 0.f, 0.f, 0.f};
#pragma unroll
  for (int nt = 0; nt < NT; nt++) acc[nt] = z;
  const unsigned short* ap = Apk + ((size_t)rb * NKS * 512 + lane * 8);
  const unsigned short* bp = Bpk + ((size_t)cb0 * NKS * 512 + lane * 8);
#pragma unroll 4
  for (int ks = 0; ks < NKS; ks++) {
    bfrag_t a = *(const bfrag_t*)(ap + ks * 512);
#pragma unroll
    for (int nt = 0; nt < NT; nt++) {
      bfrag_t b = *(const bfrag_t*)(bp + (size_t)(nt * NKS + ks) * 512);
      acc[nt] = __builtin_amdgcn_mfma_f32_16x16x32_bf16(a, b, acc[nt], 0, 0, 0);
    }
  }
}

// ---------------- QKV GEMM (layer 0 only): grid 1440 ----------------
__global__ __launch_bounds__(256)
void qkv_kernel(const unsigned short* __restrict__ qkpk,
                const unsigned short* __restrict__ outpk,
                const unsigned short* __restrict__ Wl,
                const float* __restrict__ pb, int l,
                unsigned short* __restrict__ QKV) {
  int scene = blockIdx.x & 7, r = blockIdx.x >> 3;
  int rbg = r % 15, cgall = r / 15;           // cgall 0..11
  int wave = threadIdx.x >> 6, lane = threadIdx.x & 63;
  int rb = scene * 60 + rbg * 4 + wave;
  int sel = cgall >> 2, cg = cgall & 3;
  const unsigned short* A = (sel < 2) ? qkpk : outpk;
  const unsigned short* B = Wl + sel * 65536;
  const float* bias = pb + sel * 1024 + l * 256;
  accfrag_t acc[4];
  wavegemm<8,4>(A, B, rb, cg * 4, acc);
  int l16 = lane & 15, lq = lane >> 4;
  unsigned short* C = QKV + (size_t)sel * BT * DD;
#pragma unroll
  for (int nt = 0; nt < 4; nt++) {
    int col = cg * 64 + nt * 16 + l16;
    float bv = bias[col];
#pragma unroll
    for (int r4 = 0; r4 < 4; r4++) {
      int row = rb * 16 + lq * 4 + r4;
      C[(size_t)row * DD + col] = f2b(acc[nt][r4] + bv);
    }
  }
}

// ---------------- attention (packed output) ----------------
__global__ __launch_bounds__(256)
void attn_kernel(const unsigned short* __restrict__ QKV,
                 const int* __restrict__ idx,
                 unsigned short* __restrict__ attnpk) {
  __shared__ unsigned short kn[KNN][DD + 8];
  __shared__ unsigned short vn[KNN][DD + 8];
  __shared__ float qs[DD];
  __shared__ float att[HH][KNN];
  __shared__ int nb[KNN];
  const unsigned short* Q = QKV;
  const unsigned short* K = QKV + (size_t)BT * DD;
  const unsigned short* V = QKV + 2 * (size_t)BT * DD;
  int n = swiz_tok(blockIdx.x), tid = threadIdx.x;
  if (tid < KNN) nb[tid] = idx[n * KNN + tid];
  qs[tid] = b2f(Q[(size_t)n * DD + tid]);
  __syncthreads();
#pragma unroll
  for (int p = 0; p < 4; p++) {
    int e = p * 256 + tid;
    int r = e >> 5, c8 = (e & 31) * 8;
    int srow = nb[r];
    *(uint4*)(&kn[r][c8]) = *(const uint4*)(K + (size_t)srow * DD + c8);
    *(uint4*)(&vn[r][c8]) = *(const uint4*)(V + (size_t)srow * DD + c8);
  }
  __syncthreads();
  int h = tid >> 5, kk = tid & 31;
  float dot = 0.0f;
#pragma unroll
  for (int d = 0; d < HD; d++) dot += qs[h * HD + d] * b2f(kn[kk][h * HD + d]);
  float sc = dot * SCALE_ATT;
  float mx = sc;
#pragma unroll
  for (int o = 16; o > 0; o >>= 1) mx = fmaxf(mx, __shfl_xor(mx, o, 32));
  float ex = expf(sc - mx);
  float sm = ex;
#pragma unroll
  for (int o = 16; o > 0; o >>= 1) sm += __shfl_xor(sm, o, 32);
  att[h][kk] = ex / sm;
  __syncthreads();
  int d = kk;
  float oacc = 0.0f;
#pragma unroll
  for (int k2 = 0; k2 < KNN; k2++) oacc += att[h][k2] * b2f(vn[k2][h * HD + d]);
  attnpk[pk_addr(n, tid, 8)] = f2b(oacc);
}

// ---------------- fused block: Wo+resid+LN1 -> FFN1 -> FFN2+resid+LN2 [-> next QKV] ----------------
// R8-proven structure: grid 480 x 256 threads (4 waves). One block = one 16-row block.
template<bool LAST>
__global__ __launch_bounds__(256)
void ffn_block_kernel(const unsigned short* __restrict__ attnpk,
                      const unsigned short* __restrict__ Wo,
                      const unsigned short* __restrict__ W1,
                      const unsigned short* __restrict__ W2,
                      const unsigned short* __restrict__ Wn,   // next-layer Wqkv (packed)
                      const float* __restrict__ bo,
                      const float* __restrict__ b1,
                      const float* __restrict__ b2,
                      const float* __restrict__ pb, int ln,    // bias base, next layer idx
                      float* __restrict__ yf,                  // residual stream (f32)
                      const unsigned short* __restrict__ pe_b,
                      const float* __restrict__ g1, const float* __restrict__ t1,
                      const float* __restrict__ g2, const float* __restrict__ t2,
                      unsigned short* __restrict__ QKV,
                      void* __restrict__ dout, const int* __restrict__ flag) {
  __shared__ unsigned short xls[8 * 512];    // 16r x 256k packed (NKS=8), 8 KB
  __shared__ unsigned short hls[32 * 512];   // 16r x 1024k packed (NKS=32), 32 KB
  __shared__ float ps1[4][16], ps2[4][16];
  int scene = blockIdx.x & 7, rbs = blockIdx.x >> 3;   // rbs 0..59
  int wave = threadIdx.x >> 6, lane = threadIdx.x & 63;
  int rb = scene * 60 + rbs;
  int l16 = lane & 15, lq = lane >> 4;

  // ---- residual prefetch (issue loads before the GEMM; consumed in LN1 epilogue)
  float resv[4][4];
#pragma unroll
  for (int nt = 0; nt < 4; nt++) {
    int col = wave * 64 + nt * 16 + l16;
#pragma unroll
    for (int r4 = 0; r4 < 4; r4++) {
      int row = rb * 16 + lq * 4 + r4;
      resv[nt][r4] = yf[(size_t)row * DD + col];
    }
  }

  // ---- phase 1: Wo GEMM + bias + residual + LN1 -> y (regs) + xls (LDS packed)
  accfrag_t acc[4];
  wavegemm<8,4>(attnpk, Wo, rb, wave * 4, acc);
  float y[4][4];
  float s[4] = {0.f, 0.f, 0.f, 0.f}, s2[4] = {0.f, 0.f, 0.f, 0.f};
#pragma unroll
  for (int nt = 0; nt < 4; nt++) {
    int col = wave * 64 + nt * 16 + l16;
    float bv = bo[col];
#pragma unroll
    for (int r4 = 0; r4 < 4; r4++) {
      float x = acc[nt][r4] + bv + resv[nt][r4];
      y[nt][r4] = x; s[r4] += x; s2[r4] += x * x;
    }
  }
#pragma unroll
  for (int o = 1; o < 16; o <<= 1) {
#pragma unroll
    for (int r4 = 0; r4 < 4; r4++) { s[r4] += __shfl_xor(s[r4], o); s2[r4] += __shfl_xor(s2[r4], o); }
  }
  if (l16 == 0) {
#pragma unroll
    for (int r4 = 0; r4 < 4; r4++) { ps1[wave][lq * 4 + r4] = s[r4]; ps2[wave][lq * 4 + r4] = s2[r4]; }
  }
  __syncthreads();
#pragma unroll
  for (int r4 = 0; r4 < 4; r4++) {
    int r16 = lq * 4 + r4;
    float ts  = ps1[0][r16] + ps1[1][r16] + ps1[2][r16] + ps1[3][r16];
    float ts2 = ps2[0][r16] + ps2[1][r16] + ps2[2][r16] + ps2[3][r16];
    float mu = ts * (1.0f / 256.0f);
    float var = ts2 * (1.0f / 256.0f) - mu * mu;
    float rstd = 1.0f / sqrtf(fmaxf(var, 0.f) + 1e-5f);
#pragma unroll
    for (int nt = 0; nt < 4; nt++) {
      int col = wave * 64 + nt * 16 + l16;
      float v = (y[nt][r4] - mu) * rstd * g1[col] + t1[col];
      y[nt][r4] = v;
      xls[pk_addr(r16, col, 8)] = f2b(v);
    }
  }
  __syncthreads();

  // ---- phase 2: FFN1 (xls @ W1 + b1, ReLU) -> hls (LDS packed)
#pragma unroll
  for (int i = 0; i < 4; i++) {
    int cg = wave * 4 + i;
    accfrag_t a2[4];
    wavegemm<8,4>(xls, W1, 0, cg * 4, a2);
#pragma unroll
    for (int nt = 0; nt < 4; nt++) {
      int col = cg * 64 + nt * 16 + l16;
      float bv = b1[col];
#pragma unroll
      for (int r4 = 0; r4 < 4; r4++)
        hls[pk_addr(lq * 4 + r4, col, 32)] = f2b(fmaxf(a2[nt][r4] + bv, 0.0f));
    }
  }
  __syncthreads();

  // ---- phase 3: FFN2 (hls @ W2 + b2) + residual(y) + LN2
  accfrag_t a3[4];
  wavegemm<32,4>(hls, W2, 0, wave * 4, a3);
  float v2[4][4];
  float s3[4] = {0.f, 0.f, 0.f, 0.f}, s4[4] = {0.f, 0.f, 0.f, 0.f};
#pragma unroll
  for (int nt = 0; nt < 4; nt++) {
    int col = wave * 64 + nt * 16 + l16;
    float bv = b2[col];
#pragma unroll
    for (int r4 = 0; r4 < 4; r4++) {
      float x = a3[nt][r4] + bv + y[nt][r4];
      v2[nt][r4] = x; s3[r4] += x; s4[r4] += x * x;
    }
  }
#pragma unroll
  for (int o = 1; o < 16; o <<= 1) {
#pragma unroll
    for (int r4 = 0; r4 < 4; r4++) { s3[r4] += __shfl_xor(s3[r4], o); s4[r4] += __shfl_xor(s4[r4], o); }
  }
  if (l16 == 0) {
#pragma unroll
    for (int r4 = 0; r4 < 4; r4++) { ps1[wave][lq * 4 + r4] = s3[r4]; ps2[wave][lq * 4 + r4] = s4[r4]; }
  }
  __syncthreads();     // after this barrier all waves are done reading hls (phase-3 GEMM)
  unsigned short* qkls = hls;   // reuse first 8 KB of hls for packed (y+pe)
  int fl = LAST ? *flag : 0;
#pragma unroll
  for (int r4 = 0; r4 < 4; r4++) {
    int r16 = lq * 4 + r4;
    float ts  = ps1[0][r16] + ps1[1][r16] + ps1[2][r16] + ps1[3][r16];
    float ts2 = ps2[0][r16] + ps2[1][r16] + ps2[2][r16] + ps2[3][r16];
    float mu = ts * (1.0f / 256.0f);
    float var = ts2 * (1.0f / 256.0f) - mu * mu;
    float rstd = 1.0f / sqrtf(fmaxf(var, 0.f) + 1e-5f);
#pragma unroll
    for (int nt = 0; nt < 4; nt++) {
      int col = wave * 64 + nt * 16 + l16;
      float yv = (v2[nt][r4] - mu) * rstd * g2[col] + t2[col];
      int row = rb * 16 + r16;
      if (!LAST) {
        yf[(size_t)row * DD + col] = yv;           // residual for next layer
        float q = yv + b2f(pe_b[(size_t)row * DD + col]);
        xls[pk_addr(r16, col, 8)] = f2b(yv);       // out (for V projection)
        qkls[pk_addr(r16, col, 8)] = f2b(q);       // out+pe (for Q/K projection)
      } else {
        int t = rbs * 16 + r16;   // token within scene
        size_t o;
        if (t < MTOK)             o = (size_t)(scene * MTOK + t) * DD + col;
        else if (t < MTOK + NTOK) o = (size_t)BB * MTOK * DD + (size_t)(scene * NTOK + (t - MTOK)) * DD + col;
        else                      o = (size_t)BB * MTOK * DD + (size_t)BB * NTOK * DD
                                    + (size_t)(scene * LTOK + (t - MTOK - NTOK)) * DD + col;
        if (fl) ((unsigned short*)dout)[o] = f2b(yv);
        else    ((float*)dout)[o] = yv;
      }
    }
  }

  // ---- phase 4 (!LAST): next-layer QKV projection straight from LDS
  if (!LAST) {
    __syncthreads();
#pragma unroll
    for (int i = 0; i < 3; i++) {
      int cgall = wave * 3 + i;            // 12 tiles: Q(0-3) K(4-7) V(8-11)
      int sel = cgall >> 2, cg = cgall & 3;
      const unsigned short* A = (sel < 2) ? qkls : xls;
      accfrag_t a4[4];
      wavegemm<8,4>(A, Wn + sel * 65536, 0, cg * 4, a4);
      const float* bias = pb + sel * 1024 + ln * 256;
      unsigned short* C = QKV + (size_t)sel * BT * DD;
#pragma unroll
      for (int nt = 0; nt < 4; nt++) {
        int col = cg * 64 + nt * 16 + l16;
        float bv = bias[col];
#pragma unroll
        for (int r4 = 0; r4 < 4; r4++) {
          int row = rb * 16 + lq * 4 + r4;
          C[(size_t)row * DD + col] = f2b(a4[nt][r4] + bv);
        }
      }
    }
  }
}

// ---------------- launcher ----------------
extern "C" void kernel_launch(void* const* d_in, const int* in_sizes, int n_in,
                              void* d_out, int out_size, void* d_ws, size_t ws_size,
                              hipStream_t stream) {
  const void* map_tok   = d_in[0];
  const void* agent_tok = d_in[1];
  const void* light_tok = d_in[2];
  const void* map_pos   = d_in[3];
  const void* agent_pos = d_in[4];
  const void* light_pos = d_in[5];
  const void* Wq  = d_in[9];
  const void* bq  = d_in[10];
  const void* Wk  = d_in[11];
  const void* bk  = d_in[12];
  const void* Wv  = d_in[13];
  const void* bv  = d_in[14];
  const void* Wo  = d_in[15];
  const void* bo  = d_in[16];
  const void* W1  = d_in[17];
  const void* b1  = d_in[18];
  const void* W2  = d_in[19];
  const void* b2  = d_in[20];
  const void* ln1s = d_in[21];
  const void* ln1b = d_in[22];
  const void* ln2s = d_in[23];
  const void* ln2b = d_in[24];

  size_t off = 0;
  char* base = (char*)d_ws;
  auto take = [&](size_t bytes) { char* p = base + off; off += (bytes + 255) & ~(size_t)255; return (void*)p; };
  int*   flag  = (int*)take(256);
  float* pbuf  = (float*)take((size_t)FB_TOTAL * 4);
  unsigned short* pe_b = (unsigned short*)take((size_t)BT * DD * 2);
  float* out_f = (float*)take((size_t)BT * DD * 4);   // residual stream (f32)
  unsigned short* pk1  = (unsigned short*)take((size_t)BT * DD * 2);  // layer-0 x packed
  unsigned short* qkpk = (unsigned short*)take((size_t)BT * DD * 2);  // layer-0 x+pe packed
  unsigned short* QKV  = (unsigned short*)take((size_t)3 * BT * DD * 2);
  unsigned short* attnpk = (unsigned short*)take((size_t)BT * DD * 2);
  int* idxb = (int*)take((size_t)BT * KNN * 4);
  unsigned short* Wqkvpk = (unsigned short*)take((size_t)NLAYERS * 3 * DD * DD * 2);
  unsigned short* Wopk   = (unsigned short*)take((size_t)NLAYERS * DD * DD * 2);
  unsigned short* W1pk   = (unsigned short*)take((size_t)NLAYERS * DD * FFD * 2);
  unsigned short* W2pk   = (unsigned short*)take((size_t)NLAYERS * DD * FFD * 2);

  PackSrc pw; pw.s[0]=Wq; pw.s[1]=Wk; pw.s[2]=Wv; pw.s[3]=Wo; pw.s[4]=W1; pw.s[5]=W2;
  ParamSrc ps; ps.p[0]=bq; ps.p[1]=bk; ps.p[2]=bv; ps.p[3]=bo; ps.p[4]=b1;
  ps.p[5]=b2; ps.p[6]=ln1s; ps.p[7]=ln1b; ps.p[8]=ln2s; ps.p[9]=ln2b;
  ps.p[10]=map_pos; ps.p[11]=agent_pos; ps.p[12]=light_pos;

  mega_kernel<<<21940, 256, 0, stream>>>(pw, ps, map_tok, agent_tok, light_tok, flag,
                                         Wqkvpk, Wopk, W1pk, W2pk,
                                         pe_b, out_f, pk1, qkpk, idxb, pbuf);

  qkv_kernel<<<1440, 256, 0, stream>>>(qkpk, pk1, Wqkvpk, pbuf, 0, QKV);

  for (int l = 0; l < NLAYERS; l++) {
    attn_kernel<<<BT, 256, 0, stream>>>(QKV, idxb, attnpk);
    if (l < NLAYERS - 1)
      ffn_block_kernel<false><<<480, 256, 0, stream>>>(
          attnpk, Wopk + (size_t)l * 65536, W1pk + (size_t)l * 262144, W2pk + (size_t)l * 262144,
          Wqkvpk + (size_t)(l + 1) * 196608,
          pbuf + FB_BO + l * 256, pbuf + FB_B1 + l * 1024, pbuf + FB_B2 + l * 256,
          pbuf, l + 1,
          out_f, pe_b,
          pbuf + FB_LN1S + l * 256, pbuf + FB_LN1B + l * 256,
          pbuf + FB_LN2S + l * 256, pbuf + FB_LN2B + l * 256,
          QKV, d_out, flag);
    else
      ffn_block_kernel<true><<<480, 256, 0, stream>>>(
          attnpk, Wopk + (size_t)l * 65536, W1pk + (size_t)l * 262144, W2pk + (size_t)l * 262144,
          Wqkvpk,
          pbuf + FB_BO + l * 256, pbuf + FB_B1 + l * 1024, pbuf + FB_B2 + l * 256,
          pbuf, 0,
          out_f, pe_b,
          pbuf + FB_LN1S + l * 256, pbuf + FB_LN1B + l * 256,
          pbuf + FB_LN2S + l * 256, pbuf + FB_LN2B + l * 256,
          QKV, d_out, flag);
  }
}

// Round 12
// 407.669 us; speedup vs baseline: 1.1238x; 1.1015x over previous
//
#include <hip/hip_runtime.h>
#include <math.h>

#define BB 8
#define MTOK 768
#define NTOK 128
#define LTOK 64
#define TT 960          // MTOK+NTOK+LTOK
#define BT 7680         // BB*TT
#define DD 256
#define HH 8
#define HD 32
#define KNN 32
#define FFD 1024
#define NLAYERS 4
#define SCALE_ATT 0.17677669529663687f  // 1/sqrt(32)

typedef __attribute__((ext_vector_type(8))) short bfrag_t;   // 8 bf16 (4 VGPRs)
typedef __attribute__((ext_vector_type(4))) float accfrag_t; // 4 fp32 acc

__device__ __forceinline__ float b2f(unsigned short u) {
  union { unsigned int i; float f; } c; c.i = ((unsigned int)u) << 16; return c.f;
}
__device__ __forceinline__ unsigned short f2b(float f) {
  union { float f; unsigned int i; } c; c.f = f;
  return (unsigned short)((c.i + 0x7fffu + ((c.i >> 16) & 1u)) >> 16);
}
__device__ __forceinline__ float load_elem(const void* p, size_t i, int f) {
  return f ? b2f(((const unsigned short*)p)[i]) : ((const float*)p)[i];
}
// fragment-packed layout: element (row,k[col]) of [R x K] ->
//   ((row/16)*NKS + k/32)*512 + (((k>>3)&3)*16 + row%16)*8 + k%8
__device__ __forceinline__ size_t pk_addr(int row, int col, int nks) {
  return ((size_t)((row >> 4) * nks + (col >> 5)) << 9)
       + (size_t)(((((col >> 3) & 3) << 4) + (row & 15)) * 8 + (col & 7));
}
// scene->XCD swizzle
__device__ __forceinline__ int swiz_tok(int blk) { return (blk & 7) * TT + (blk >> 3); }

// ---------------- positions + params -> fp32 (with inline dtype detect) ----------------
#define FB_BQ 0
#define FB_BK 1024
#define FB_BV 2048
#define FB_BO 3072
#define FB_B1 4096
#define FB_B2 8192
#define FB_LN1S 9216
#define FB_LN1B 10240
#define FB_LN2S 11264
#define FB_LN2B 12288
#define FB_TOTAL 13312
struct ParamSrc { const void* p[13]; };
__global__ __launch_bounds__(256)
void conv_misc_kernel(ParamSrc ps, const void* tok, int* flagout,
                      float* __restrict__ dst, float* __restrict__ posf) {
  __shared__ int cnt;
  if (threadIdx.x == 0) cnt = 0;
  __syncthreads();
  const unsigned short* u = (const unsigned short*)tok;
  int ok = 0;
  for (int i = threadIdx.x; i < 1024; i += 256) {
    int e = (u[i] >> 7) & 0xFF;
    if (e >= 100 && e <= 140) ok++;
  }
  atomicAdd(&cnt, ok);
  __syncthreads();
  int f = (cnt >= 922) ? 1 : 0;
  if (blockIdx.x == 0 && threadIdx.x == 0) *flagout = f;
  if (blockIdx.x < BB) {
    int b = blockIdx.x;
    for (int t = threadIdx.x; t < TT * 2; t += 256) {
      int tok2 = t >> 1, c = t & 1;
      const void* p; size_t idx;
      if (tok2 < MTOK)             { p = ps.p[10]; idx = (size_t)(b * MTOK + tok2) * 2 + c; }
      else if (tok2 < MTOK + NTOK) { p = ps.p[11]; idx = (size_t)(b * NTOK + tok2 - MTOK) * 2 + c; }
      else                         { p = ps.p[12]; idx = (size_t)(b * LTOK + tok2 - MTOK - NTOK) * 2 + c; }
      posf[((size_t)b * TT + tok2) * 2 + c] = load_elem(p, idx, f);
    }
    return;
  }
  int i = (blockIdx.x - BB) * 256 + threadIdx.x;
  if (i >= FB_TOTAL) return;
  int src; size_t off;
  if (i < 4096)      { src = i >> 10;              off = i & 1023; }
  else if (i < 8192) { src = 4;                    off = i - 4096; }
  else               { src = 5 + ((i - 8192) >> 10); off = (i - 8192) & 1023; }
  dst[i] = load_elem(ps.p[src], off, f);
}

// ---------------- KNN helpers ----------------
__device__ __forceinline__ unsigned long long shfl_xor_u64(unsigned long long v, int m) {
  unsigned lo = (unsigned)v, hi = (unsigned)(v >> 32);
  lo = (unsigned)__shfl_xor((int)lo, m);
  hi = (unsigned)__shfl_xor((int)hi, m);
  return ((unsigned long long)hi << 32) | (unsigned long long)lo;
}
__device__ __forceinline__ unsigned long long shfl_u64(unsigned long long v, int srcLane) {
  unsigned lo = (unsigned)v, hi = (unsigned)(v >> 32);
  lo = (unsigned)__shfl((int)lo, srcLane);
  hi = (unsigned)__shfl((int)hi, srcLane);
  return ((unsigned long long)hi << 32) | (unsigned long long)lo;
}
__device__ __forceinline__ unsigned long long bitonic64(unsigned long long key, int lane) {
#pragma unroll
  for (int kk = 2; kk <= 64; kk <<= 1) {
#pragma unroll
    for (int j = kk >> 1; j > 0; j >>= 1) {
      unsigned long long other = shfl_xor_u64(key, j);
      bool small_ = (lane & j) == 0;
      bool dir = (lane & kk) == 0;
      bool keep = ((key < other) == (small_ == dir));
      key = keep ? key : other;
    }
  }
  return key;
}

// ---------------- mega setup: packW (coalesced) + prep + knn in one dispatch ----------------
// grid = 12288 (packW) + 7680 (prep) + 1920 (knn) = 21888
struct PackSrc { const void* s[6]; };
__global__ __launch_bounds__(256)
void mega_kernel(PackSrc w, const void* mt, const void* at, const void* lt,
                 const float* __restrict__ posf, const int* __restrict__ flag,
                 unsigned short* __restrict__ Wqkvpk, unsigned short* __restrict__ Wopk,
                 unsigned short* __restrict__ W1pk, unsigned short* __restrict__ W2pk,
                 unsigned short* __restrict__ pe_b, float* __restrict__ out_f,
                 unsigned short* __restrict__ pk1, unsigned short* __restrict__ qkpk,
                 int* __restrict__ idx_out) {
  __shared__ float sx[TT], sy[TT];
  __shared__ unsigned long long cbuf[4][64];
  int bid = blockIdx.x;
  if (bid < 12288) {
    // ---- packW: source-linear enumeration -> coalesced reads, local scatter writes
    int f = *flag;
    int id = bid * 256 + threadIdx.x;
    if (id < 786432) {                  // Wq,Wk,Wv (K=256,N=256)
      int layer = id / 196608, rest = id % 196608;
      int sel = rest >> 16, e = rest & 65535;
      int k = e >> 8, col = e & 255;
      const void* src = w.s[sel];
      size_t si = (size_t)layer * 65536 + e;
      Wqkvpk[(size_t)layer * 196608 + (size_t)sel * 65536 + pk_addr(col, k, 8)] =
          f ? ((const unsigned short*)src)[si] : f2b(((const float*)src)[si]);
    } else if (id < 1048576) {          // Wo (K=256,N=256)
      int off = id - 786432, layer = off >> 16, e = off & 65535;
      int k = e >> 8, col = e & 255;
      size_t si = (size_t)layer * 65536 + e;
      Wopk[(size_t)layer * 65536 + pk_addr(col, k, 8)] =
          f ? ((const unsigned short*)w.s[3])[si] : f2b(((const float*)w.s[3])[si]);
    } else if (id < 2097152) {          // W1 (K=256,N=1024)
      int off = id - 1048576, layer = off >> 18, e = off & 262143;
      int k = e >> 10, col = e & 1023;
      size_t si = (size_t)layer * 262144 + e;
      W1pk[(size_t)layer * 262144 + pk_addr(col, k, 8)] =
          f ? ((const unsigned short*)w.s[4])[si] : f2b(((const float*)w.s[4])[si]);
    } else {                            // W2 (K=1024,N=256)
      int off = id - 2097152, layer = off >> 18, e = off & 262143;
      int k = e >> 8, col = e & 255;
      size_t si = (size_t)layer * 262144 + e;
      W2pk[(size_t)layer * 262144 + pk_addr(col, k, 32)] =
          f ? ((const unsigned short*)w.s[5])[si] : f2b(((const float*)w.s[5])[si]);
    }
    return;
  }
  if (bid < 19968) {
    // ---- prep: positional embedding + stream init
    // trig fast path: 10000^(-expo) via exp2f (HW v_exp), __sinf/__cosf (HW v_sin/v_cos).
    int n = swiz_tok(bid - 12288), d = threadIdx.x;
    int b = n / TT, t = n - b * TT;
    int f = *flag;
    const void* src; size_t si;
    if (t < MTOK)              { src = mt; si = (size_t)(b * MTOK + t) * DD + d; }
    else if (t < MTOK + NTOK)  { src = at; si = (size_t)(b * NTOK + (t - MTOK)) * DD + d; }
    else                       { src = lt; si = (size_t)(b * LTOK + (t - MTOK - NTOK)) * DD + d; }
    float x = load_elem(src, si, f);
    float px = posf[((size_t)b * TT + t) * 2 + 0];
    float py = posf[((size_t)b * TT + t) * 2 + 1];
    float coord = (d < 128) ? py : px;
    int j = d & 127;
    float expo = (float)(2 * (j >> 1)) / 128.0f;
    // 2*pi / 10000^expo = 2*pi * 2^(-expo*log2(10000))
    float fct = 6.283185307179586f * exp2f(expo * -13.287712379549449f);
    float e = coord * fct;
    float p = (j & 1) ? __cosf(e) : __sinf(e);
    size_t o = (size_t)n * DD + d;
    pe_b[o] = f2b(p);
    out_f[o] = x;
    size_t pa = pk_addr(n, d, 8);
    pk1[pa] = f2b(x);
    qkpk[pa] = f2b(x + p);
    return;
  }
  // ---- knn: threshold-prune + bitonic top-32 (exact)
  int kb = bid - 19968;
  int b = kb & 7;
  int qbase = (kb >> 3) * 4;
  for (int t = threadIdx.x; t < TT; t += 256) {
    sx[t] = posf[((size_t)b * TT + t) * 2 + 0];
    sy[t] = posf[((size_t)b * TT + t) * 2 + 1];
  }
  __syncthreads();
  int wave = threadIdx.x >> 6, lane = threadIdx.x & 63;
  int t = qbase + wave;
  float qx = sx[t], qy = sy[t];

  unsigned long long k[15];
#pragma unroll
  for (int c = 0; c < 15; c++) {
    int j = c * 64 + lane;
    float dx = qx - sx[j], dy = qy - sy[j];
    float d2 = __fadd_rn(__fmul_rn(dx, dx), __fmul_rn(dy, dy));
    k[c] = ((unsigned long long)__float_as_uint(d2) << 32) | (unsigned)j;
  }
  unsigned long long lm = k[0];
#pragma unroll
  for (int c = 1; c < 15; c++) lm = (k[c] < lm) ? k[c] : lm;

  unsigned long long sm = bitonic64(lm, lane);
  unsigned long long thr = shfl_u64(sm, 31);

  int c_l = 0;
#pragma unroll
  for (int c = 0; c < 15; c++) c_l += (k[c] <= thr) ? 1 : 0;
  int inc = c_l;
#pragma unroll
  for (int o = 1; o < 64; o <<= 1) {
    int tt = __shfl_up(inc, o);
    inc += (lane >= o) ? tt : 0;
  }
  int total = __shfl(inc, 63);
  int pos = inc - c_l;

  if (total <= 64) {
    unsigned long long* wb = cbuf[wave];
#pragma unroll
    for (int c = 0; c < 15; c++) {
      if (k[c] <= thr) { wb[pos] = k[c]; pos++; }
    }
    unsigned long long cand = (lane < total) ? wb[lane] : ~0ull;
    cand = bitonic64(cand, lane);
    if (lane < KNN)
      idx_out[((size_t)(b * TT + t)) * KNN + lane] = b * TT + (int)(cand & 0xFFFFFFFFu);
  } else {
    unsigned res = 0;
    for (int i = 0; i < KNN; i++) {
      unsigned long long m = k[0];
#pragma unroll
      for (int c = 1; c < 15; c++) m = (k[c] < m) ? k[c] : m;
#pragma unroll
      for (int o = 32; o > 0; o >>= 1) {
        unsigned long long om = shfl_xor_u64(m, o);
        m = (om < m) ? om : m;
      }
      if (lane == i) res = (unsigned)(m & 0xFFFFFFFFu);
      int owner = (int)(m & 63u), ch = (int)(((unsigned)(m & 0xFFFFFFFFu)) >> 6);
      if (lane == owner) {
#pragma unroll
        for (int c = 0; c < 15; c++) if (c == ch) k[c] = ~0ull;
      }
    }
    if (lane < KNN)
      idx_out[((size_t)(b * TT + t)) * KNN + lane] = b * TT + (int)res;
  }
}

// ---------------- wave GEMM: 16 rows x NT*16 cols ----------------
template<int NKS, int NT>
__device__ __forceinline__ void wavegemm(const unsigned short* __restrict__ Apk,
                                         const unsigned short* __restrict__ Bpk,
                                         int rb, int cb0, accfrag_t (&acc)[NT]) {
  const int lane = threadIdx.x & 63;
  accfrag_t z = {0.f, 0.f, 0.f, 0.f};
#pragma unroll
  for (int nt = 0; nt < NT; nt++) acc[nt] = z;
  const unsigned short* ap = Apk + ((size_t)rb * NKS * 512 + lane * 8);
  const unsigned short* bp = Bpk + ((size_t)cb0 * NKS * 512 + lane * 8);
#pragma unroll 4
  for (int ks = 0; ks < NKS; ks++) {
    bfrag_t a = *(const bfrag_t*)(ap + ks * 512);
#pragma unroll
    for (int nt = 0; nt < NT; nt++) {
      bfrag_t b = *(const bfrag_t*)(bp + (size_t)(nt * NKS + ks) * 512);
      acc[nt] = __builtin_amdgcn_mfma_f32_16x16x32_bf16(a, b, acc[nt], 0, 0, 0);
    }
  }
}

// ---------------- QKV GEMM (layer 0 only): grid 1440 ----------------
__global__ __launch_bounds__(256)
void qkv_kernel(const unsigned short* __restrict__ qkpk,
                const unsigned short* __restrict__ outpk,
                const unsigned short* __restrict__ Wl,
                const float* __restrict__ pb, int l,
                unsigned short* __restrict__ QKV) {
  int scene = blockIdx.x & 7, r = blockIdx.x >> 3;
  int rbg = r % 15, cgall = r / 15;           // cgall 0..11
  int wave = threadIdx.x >> 6, lane = threadIdx.x & 63;
  int rb = scene * 60 + rbg * 4 + wave;
  int sel = cgall >> 2, cg = cgall & 3;
  const unsigned short* A = (sel < 2) ? qkpk : outpk;
  const unsigned short* B = Wl + sel * 65536;
  const float* bias = pb + sel * 1024 + l * 256;
  accfrag_t acc[4];
  wavegemm<8,4>(A, B, rb, cg * 4, acc);
  int l16 = lane & 15, lq = lane >> 4;
  unsigned short* C = QKV + (size_t)sel * BT * DD;
#pragma unroll
  for (int nt = 0; nt < 4; nt++) {
    int col = cg * 64 + nt * 16 + l16;
    float bv = bias[col];
#pragma unroll
    for (int r4 = 0; r4 < 4; r4++) {
      int row = rb * 16 + lq * 4 + r4;
      C[(size_t)row * DD + col] = f2b(acc[nt][r4] + bv);
    }
  }
}

// ---------------- attention (packed output) ----------------
__global__ __launch_bounds__(256)
void attn_kernel(const unsigned short* __restrict__ QKV,
                 const int* __restrict__ idx,
                 unsigned short* __restrict__ attnpk) {
  __shared__ unsigned short kn[KNN][DD + 8];
  __shared__ unsigned short vn[KNN][DD + 8];
  __shared__ float qs[DD];
  __shared__ float att[HH][KNN];
  __shared__ int nb[KNN];
  const unsigned short* Q = QKV;
  const unsigned short* K = QKV + (size_t)BT * DD;
  const unsigned short* V = QKV + 2 * (size_t)BT * DD;
  int n = swiz_tok(blockIdx.x), tid = threadIdx.x;
  if (tid < KNN) nb[tid] = idx[n * KNN + tid];
  qs[tid] = b2f(Q[(size_t)n * DD + tid]);
  __syncthreads();
#pragma unroll
  for (int p = 0; p < 4; p++) {
    int e = p * 256 + tid;
    int r = e >> 5, c8 = (e & 31) * 8;
    int srow = nb[r];
    *(uint4*)(&kn[r][c8]) = *(const uint4*)(K + (size_t)srow * DD + c8);
    *(uint4*)(&vn[r][c8]) = *(const uint4*)(V + (size_t)srow * DD + c8);
  }
  __syncthreads();
  int h = tid >> 5, kk = tid & 31;
  float dot = 0.0f;
#pragma unroll
  for (int d = 0; d < HD; d++) dot += qs[h * HD + d] * b2f(kn[kk][h * HD + d]);
  float sc = dot * SCALE_ATT;
  float mx = sc;
#pragma unroll
  for (int o = 16; o > 0; o >>= 1) mx = fmaxf(mx, __shfl_xor(mx, o, 32));
  float ex = expf(sc - mx);
  float sm = ex;
#pragma unroll
  for (int o = 16; o > 0; o >>= 1) sm += __shfl_xor(sm, o, 32);
  att[h][kk] = ex / sm;
  __syncthreads();
  int d = kk;
  float oacc = 0.0f;
#pragma unroll
  for (int k2 = 0; k2 < KNN; k2++) oacc += att[h][k2] * b2f(vn[k2][h * HD + d]);
  attnpk[pk_addr(n, tid, 8)] = f2b(oacc);
}

// ---------------- fused block: Wo+resid+LN1 -> FFN1 -> FFN2+resid+LN2 [-> next QKV] ----------------
// R8-proven structure: grid 480 x 256 threads (4 waves). One block = one 16-row block.
template<bool LAST>
__global__ __launch_bounds__(256)
void ffn_block_kernel(const unsigned short* __restrict__ attnpk,
                      const unsigned short* __restrict__ Wo,
                      const unsigned short* __restrict__ W1,
                      const unsigned short* __restrict__ W2,
                      const unsigned short* __restrict__ Wn,   // next-layer Wqkv (packed)
                      const float* __restrict__ bo,
                      const float* __restrict__ b1,
                      const float* __restrict__ b2,
                      const float* __restrict__ pb, int ln,    // bias base, next layer idx
                      float* __restrict__ yf,                  // residual stream (f32)
                      const unsigned short* __restrict__ pe_b,
                      const float* __restrict__ g1, const float* __restrict__ t1,
                      const float* __restrict__ g2, const float* __restrict__ t2,
                      unsigned short* __restrict__ QKV,
                      void* __restrict__ dout, const int* __restrict__ flag) {
  __shared__ unsigned short xls[8 * 512];    // 16r x 256k packed (NKS=8), 8 KB
  __shared__ unsigned short hls[32 * 512];   // 16r x 1024k packed (NKS=32), 32 KB
  __shared__ float ps1[4][16], ps2[4][16];
  int scene = blockIdx.x & 7, rbs = blockIdx.x >> 3;   // rbs 0..59
  int wave = threadIdx.x >> 6, lane = threadIdx.x & 63;
  int rb = scene * 60 + rbs;
  int l16 = lane & 15, lq = lane >> 4;

  // ---- residual prefetch (issue loads before the GEMM; consumed in LN1 epilogue)
  float resv[4][4];
#pragma unroll
  for (int nt = 0; nt < 4; nt++) {
    int col = wave * 64 + nt * 16 + l16;
#pragma unroll
    for (int r4 = 0; r4 < 4; r4++) {
      int row = rb * 16 + lq * 4 + r4;
      resv[nt][r4] = yf[(size_t)row * DD + col];
    }
  }

  // ---- phase 1: Wo GEMM + bias + residual + LN1 -> y (regs) + xls (LDS packed)
  accfrag_t acc[4];
  wavegemm<8,4>(attnpk, Wo, rb, wave * 4, acc);
  float y[4][4];
  float s[4] = {0.f, 0.f, 0.f, 0.f}, s2[4] = {0.f, 0.f, 0.f, 0.f};
#pragma unroll
  for (int nt = 0; nt < 4; nt++) {
    int col = wave * 64 + nt * 16 + l16;
    float bv = bo[col];
#pragma unroll
    for (int r4 = 0; r4 < 4; r4++) {
      float x = acc[nt][r4] + bv + resv[nt][r4];
      y[nt][r4] = x; s[r4] += x; s2[r4] += x * x;
    }
  }
#pragma unroll
  for (int o = 1; o < 16; o <<= 1) {
#pragma unroll
    for (int r4 = 0; r4 < 4; r4++) { s[r4] += __shfl_xor(s[r4], o); s2[r4] += __shfl_xor(s2[r4], o); }
  }
  if (l16 == 0) {
#pragma unroll
    for (int r4 = 0; r4 < 4; r4++) { ps1[wave][lq * 4 + r4] = s[r4]; ps2[wave][lq * 4 + r4] = s2[r4]; }
  }
  __syncthreads();
#pragma unroll
  for (int r4 = 0; r4 < 4; r4++) {
    int r16 = lq * 4 + r4;
    float ts  = ps1[0][r16] + ps1[1][r16] + ps1[2][r16] + ps1[3][r16];
    float ts2 = ps2[0][r16] + ps2[1][r16] + ps2[2][r16] + ps2[3][r16];
    float mu = ts * (1.0f / 256.0f);
    float var = ts2 * (1.0f / 256.0f) - mu * mu;
    float rstd = 1.0f / sqrtf(fmaxf(var, 0.f) + 1e-5f);
#pragma unroll
    for (int nt = 0; nt < 4; nt++) {
      int col = wave * 64 + nt * 16 + l16;
      float v = (y[nt][r4] - mu) * rstd * g1[col] + t1[col];
      y[nt][r4] = v;
      xls[pk_addr(r16, col, 8)] = f2b(v);
    }
  }
  __syncthreads();

  // ---- phase 2: FFN1 (xls @ W1 + b1, ReLU) -> hls (LDS packed)
#pragma unroll
  for (int i = 0; i < 4; i++) {
    int cg = wave * 4 + i;
    accfrag_t a2[4];
    wavegemm<8,4>(xls, W1, 0, cg * 4, a2);
#pragma unroll
    for (int nt = 0; nt < 4; nt++) {
      int col = cg * 64 + nt * 16 + l16;
      float bv = b1[col];
#pragma unroll
      for (int r4 = 0; r4 < 4; r4++)
        hls[pk_addr(lq * 4 + r4, col, 32)] = f2b(fmaxf(a2[nt][r4] + bv, 0.0f));
    }
  }
  __syncthreads();

  // ---- phase 3: FFN2 (hls @ W2 + b2) + residual(y) + LN2
  accfrag_t a3[4];
  wavegemm<32,4>(hls, W2, 0, wave * 4, a3);
  float v2[4][4];
  float s3[4] = {0.f, 0.f, 0.f, 0.f}, s4[4] = {0.f, 0.f, 0.f, 0.f};
#pragma unroll
  for (int nt = 0; nt < 4; nt++) {
    int col = wave * 64 + nt * 16 + l16;
    float bv = b2[col];
#pragma unroll
    for (int r4 = 0; r4 < 4; r4++) {
      float x = a3[nt][r4] + bv + y[nt][r4];
      v2[nt][r4] = x; s3[r4] += x; s4[r4] += x * x;
    }
  }
#pragma unroll
  for (int o = 1; o < 16; o <<= 1) {
#pragma unroll
    for (int r4 = 0; r4 < 4; r4++) { s3[r4] += __shfl_xor(s3[r4], o); s4[r4] += __shfl_xor(s4[r4], o); }
  }
  if (l16 == 0) {
#pragma unroll
    for (int r4 = 0; r4 < 4; r4++) { ps1[wave][lq * 4 + r4] = s3[r4]; ps2[wave][lq * 4 + r4] = s4[r4]; }
  }
  __syncthreads();     // after this barrier all waves are done reading hls (phase-3 GEMM)
  unsigned short* qkls = hls;   // reuse first 8 KB of hls for packed (y+pe)
  int fl = LAST ? *flag : 0;
#pragma unroll
  for (int r4 = 0; r4 < 4; r4++) {
    int r16 = lq * 4 + r4;
    float ts  = ps1[0][r16] + ps1[1][r16] + ps1[2][r16] + ps1[3][r16];
    float ts2 = ps2[0][r16] + ps2[1][r16] + ps2[2][r16] + ps2[3][r16];
    float mu = ts * (1.0f / 256.0f);
    float var = ts2 * (1.0f / 256.0f) - mu * mu;
    float rstd = 1.0f / sqrtf(fmaxf(var, 0.f) + 1e-5f);
#pragma unroll
    for (int nt = 0; nt < 4; nt++) {
      int col = wave * 64 + nt * 16 + l16;
      float yv = (v2[nt][r4] - mu) * rstd * g2[col] + t2[col];
      int row = rb * 16 + r16;
      if (!LAST) {
        yf[(size_t)row * DD + col] = yv;           // residual for next layer
        float q = yv + b2f(pe_b[(size_t)row * DD + col]);
        xls[pk_addr(r16, col, 8)] = f2b(yv);       // out (for V projection)
        qkls[pk_addr(r16, col, 8)] = f2b(q);       // out+pe (for Q/K projection)
      } else {
        int t = rbs * 16 + r16;   // token within scene
        size_t o;
        if (t < MTOK)             o = (size_t)(scene * MTOK + t) * DD + col;
        else if (t < MTOK + NTOK) o = (size_t)BB * MTOK * DD + (size_t)(scene * NTOK + (t - MTOK)) * DD + col;
        else                      o = (size_t)BB * MTOK * DD + (size_t)BB * NTOK * DD
                                    + (size_t)(scene * LTOK + (t - MTOK - NTOK)) * DD + col;
        if (fl) ((unsigned short*)dout)[o] = f2b(yv);
        else    ((float*)dout)[o] = yv;
      }
    }
  }

  // ---- phase 4 (!LAST): next-layer QKV projection straight from LDS
  if (!LAST) {
    __syncthreads();
#pragma unroll
    for (int i = 0; i < 3; i++) {
      int cgall = wave * 3 + i;            // 12 tiles: Q(0-3) K(4-7) V(8-11)
      int sel = cgall >> 2, cg = cgall & 3;
      const unsigned short* A = (sel < 2) ? qkls : xls;
      accfrag_t a4[4];
      wavegemm<8,4>(A, Wn + sel * 65536, 0, cg * 4, a4);
      const float* bias = pb + sel * 1024 + ln * 256;
      unsigned short* C = QKV + (size_t)sel * BT * DD;
#pragma unroll
      for (int nt = 0; nt < 4; nt++) {
        int col = cg * 64 + nt * 16 + l16;
        float bv = bias[col];
#pragma unroll
        for (int r4 = 0; r4 < 4; r4++) {
          int row = rb * 16 + lq * 4 + r4;
          C[(size_t)row * DD + col] = f2b(a4[nt][r4] + bv);
        }
      }
    }
  }
}

// ---------------- launcher ----------------
extern "C" void kernel_launch(void* const* d_in, const int* in_sizes, int n_in,
                              void* d_out, int out_size, void* d_ws, size_t ws_size,
                              hipStream_t stream) {
  const void* map_tok   = d_in[0];
  const void* agent_tok = d_in[1];
  const void* light_tok = d_in[2];
  const void* map_pos   = d_in[3];
  const void* agent_pos = d_in[4];
  const void* light_pos = d_in[5];
  const void* Wq  = d_in[9];
  const void* bq  = d_in[10];
  const void* Wk  = d_in[11];
  const void* bk  = d_in[12];
  const void* Wv  = d_in[13];
  const void* bv  = d_in[14];
  const void* Wo  = d_in[15];
  const void* bo  = d_in[16];
  const void* W1  = d_in[17];
  const void* b1  = d_in[18];
  const void* W2  = d_in[19];
  const void* b2  = d_in[20];
  const void* ln1s = d_in[21];
  const void* ln1b = d_in[22];
  const void* ln2s = d_in[23];
  const void* ln2b = d_in[24];

  size_t off = 0;
  char* base = (char*)d_ws;
  auto take = [&](size_t bytes) { char* p = base + off; off += (bytes + 255) & ~(size_t)255; return (void*)p; };
  int*   flag  = (int*)take(256);
  float* posf  = (float*)take((size_t)BT * 2 * 4);
  float* pbuf  = (float*)take((size_t)FB_TOTAL * 4);
  unsigned short* pe_b = (unsigned short*)take((size_t)BT * DD * 2);
  float* out_f = (float*)take((size_t)BT * DD * 4);   // residual stream (f32)
  unsigned short* pk1  = (unsigned short*)take((size_t)BT * DD * 2);  // layer-0 x packed
  unsigned short* qkpk = (unsigned short*)take((size_t)BT * DD * 2);  // layer-0 x+pe packed
  unsigned short* QKV  = (unsigned short*)take((size_t)3 * BT * DD * 2);
  unsigned short* attnpk = (unsigned short*)take((size_t)BT * DD * 2);
  int* idxb = (int*)take((size_t)BT * KNN * 4);
  unsigned short* Wqkvpk = (unsigned short*)take((size_t)NLAYERS * 3 * DD * DD * 2);
  unsigned short* Wopk   = (unsigned short*)take((size_t)NLAYERS * DD * DD * 2);
  unsigned short* W1pk   = (unsigned short*)take((size_t)NLAYERS * DD * FFD * 2);
  unsigned short* W2pk   = (unsigned short*)take((size_t)NLAYERS * DD * FFD * 2);

  ParamSrc ps; ps.p[0]=bq; ps.p[1]=bk; ps.p[2]=bv; ps.p[3]=bo; ps.p[4]=b1;
  ps.p[5]=b2; ps.p[6]=ln1s; ps.p[7]=ln1b; ps.p[8]=ln2s; ps.p[9]=ln2b;
  ps.p[10]=map_pos; ps.p[11]=agent_pos; ps.p[12]=light_pos;
  conv_misc_kernel<<<BB + (FB_TOTAL + 255) / 256, 256, 0, stream>>>(ps, map_tok, flag, pbuf, posf);

  PackSrc pw; pw.s[0]=Wq; pw.s[1]=Wk; pw.s[2]=Wv; pw.s[3]=Wo; pw.s[4]=W1; pw.s[5]=W2;
  mega_kernel<<<21888, 256, 0, stream>>>(pw, map_tok, agent_tok, light_tok, posf, flag,
                                         Wqkvpk, Wopk, W1pk, W2pk,
                                         pe_b, out_f, pk1, qkpk, idxb);

  qkv_kernel<<<1440, 256, 0, stream>>>(qkpk, pk1, Wqkvpk, pbuf, 0, QKV);

  for (int l = 0; l < NLAYERS; l++) {
    attn_kernel<<<BT, 256, 0, stream>>>(QKV, idxb, attnpk);
    if (l < NLAYERS - 1)
      ffn_block_kernel<false><<<480, 256, 0, stream>>>(
          attnpk, Wopk + (size_t)l * 65536, W1pk + (size_t)l * 262144, W2pk + (size_t)l * 262144,
          Wqkvpk + (size_t)(l + 1) * 196608,
          pbuf + FB_BO + l * 256, pbuf + FB_B1 + l * 1024, pbuf + FB_B2 + l * 256,
          pbuf, l + 1,
          out_f, pe_b,
          pbuf + FB_LN1S + l * 256, pbuf + FB_LN1B + l * 256,
          pbuf + FB_LN2S + l * 256, pbuf + FB_LN2B + l * 256,
          QKV, d_out, flag);
    else
      ffn_block_kernel<true><<<480, 256, 0, stream>>>(
          attnpk, Wopk + (size_t)l * 65536, W1pk + (size_t)l * 262144, W2pk + (size_t)l * 262144,
          Wqkvpk,
          pbuf + FB_BO + l * 256, pbuf + FB_B1 + l * 1024, pbuf + FB_B2 + l * 256,
          pbuf, 0,
          out_f, pe_b,
          pbuf + FB_LN1S + l * 256, pbuf + FB_LN1B + l * 256,
          pbuf + FB_LN2S + l * 256, pbuf + FB_LN2B + l * 256,
          QKV, d_out, flag);
  }
}

// Round 13
// 385.199 us; speedup vs baseline: 1.1893x; 1.0583x over previous
//
#include <hip/hip_runtime.h>
#include <math.h>

#define BB 8
#define MTOK 768
#define NTOK 128
#define LTOK 64
#define TT 960          // MTOK+NTOK+LTOK
#define BT 7680         // BB*TT
#define DD 256
#define HH 8
#define HD 32
#define KNN 32
#define FFD 1024
#define NLAYERS 4
#define SCALE_ATT 0.17677669529663687f  // 1/sqrt(32)

typedef __attribute__((ext_vector_type(8))) short bfrag_t;   // 8 bf16 (4 VGPRs)
typedef __attribute__((ext_vector_type(4))) float accfrag_t; // 4 fp32 acc

__device__ __forceinline__ float b2f(unsigned short u) {
  union { unsigned int i; float f; } c; c.i = ((unsigned int)u) << 16; return c.f;
}
__device__ __forceinline__ unsigned short f2b(float f) {
  union { float f; unsigned int i; } c; c.f = f;
  return (unsigned short)((c.i + 0x7fffu + ((c.i >> 16) & 1u)) >> 16);
}
__device__ __forceinline__ float load_elem(const void* p, size_t i, int f) {
  return f ? b2f(((const unsigned short*)p)[i]) : ((const float*)p)[i];
}
// fragment-packed layout: element (row,k[col]) of [R x K] ->
//   ((row/16)*NKS + k/32)*512 + (((k>>3)&3)*16 + row%16)*8 + k%8
__device__ __forceinline__ size_t pk_addr(int row, int col, int nks) {
  return ((size_t)((row >> 4) * nks + (col >> 5)) << 9)
       + (size_t)(((((col >> 3) & 3) << 4) + (row & 15)) * 8 + (col & 7));
}
// scene->XCD swizzle
__device__ __forceinline__ int swiz_tok(int blk) { return (blk & 7) * TT + (blk >> 3); }

// ---------------- positions + params -> fp32 (with inline dtype detect) ----------------
#define FB_BQ 0
#define FB_BK 1024
#define FB_BV 2048
#define FB_BO 3072
#define FB_B1 4096
#define FB_B2 8192
#define FB_LN1S 9216
#define FB_LN1B 10240
#define FB_LN2S 11264
#define FB_LN2B 12288
#define FB_TOTAL 13312
struct ParamSrc { const void* p[13]; };
__global__ __launch_bounds__(256)
void conv_misc_kernel(ParamSrc ps, const void* tok, int* flagout,
                      float* __restrict__ dst, float* __restrict__ posf) {
  __shared__ int cnt;
  if (threadIdx.x == 0) cnt = 0;
  __syncthreads();
  const unsigned short* u = (const unsigned short*)tok;
  int ok = 0;
  for (int i = threadIdx.x; i < 1024; i += 256) {
    int e = (u[i] >> 7) & 0xFF;
    if (e >= 100 && e <= 140) ok++;
  }
  atomicAdd(&cnt, ok);
  __syncthreads();
  int f = (cnt >= 922) ? 1 : 0;
  if (blockIdx.x == 0 && threadIdx.x == 0) *flagout = f;
  if (blockIdx.x < BB) {
    int b = blockIdx.x;
    for (int t = threadIdx.x; t < TT * 2; t += 256) {
      int tok2 = t >> 1, c = t & 1;
      const void* p; size_t idx;
      if (tok2 < MTOK)             { p = ps.p[10]; idx = (size_t)(b * MTOK + tok2) * 2 + c; }
      else if (tok2 < MTOK + NTOK) { p = ps.p[11]; idx = (size_t)(b * NTOK + tok2 - MTOK) * 2 + c; }
      else                         { p = ps.p[12]; idx = (size_t)(b * LTOK + tok2 - MTOK - NTOK) * 2 + c; }
      posf[((size_t)b * TT + tok2) * 2 + c] = load_elem(p, idx, f);
    }
    return;
  }
  int i = (blockIdx.x - BB) * 256 + threadIdx.x;
  if (i >= FB_TOTAL) return;
  int src; size_t off;
  if (i < 4096)      { src = i >> 10;              off = i & 1023; }
  else if (i < 8192) { src = 4;                    off = i - 4096; }
  else               { src = 5 + ((i - 8192) >> 10); off = (i - 8192) & 1023; }
  dst[i] = load_elem(ps.p[src], off, f);
}

// ---------------- KNN helpers ----------------
__device__ __forceinline__ unsigned long long shfl_xor_u64(unsigned long long v, int m) {
  unsigned lo = (unsigned)v, hi = (unsigned)(v >> 32);
  lo = (unsigned)__shfl_xor((int)lo, m);
  hi = (unsigned)__shfl_xor((int)hi, m);
  return ((unsigned long long)hi << 32) | (unsigned long long)lo;
}
__device__ __forceinline__ unsigned long long shfl_u64(unsigned long long v, int srcLane) {
  unsigned lo = (unsigned)v, hi = (unsigned)(v >> 32);
  lo = (unsigned)__shfl((int)lo, srcLane);
  hi = (unsigned)__shfl((int)hi, srcLane);
  return ((unsigned long long)hi << 32) | (unsigned long long)lo;
}
__device__ __forceinline__ unsigned long long bitonic64(unsigned long long key, int lane) {
#pragma unroll
  for (int kk = 2; kk <= 64; kk <<= 1) {
#pragma unroll
    for (int j = kk >> 1; j > 0; j >>= 1) {
      unsigned long long other = shfl_xor_u64(key, j);
      bool small_ = (lane & j) == 0;
      bool dir = (lane & kk) == 0;
      bool keep = ((key < other) == (small_ == dir));
      key = keep ? key : other;
    }
  }
  return key;
}

// ---------------- mega setup: packW (coalesced) + prep + knn in one dispatch ----------------
// grid = 12288 (packW) + 7680 (prep) + 1920 (knn) = 21888
struct PackSrc { const void* s[6]; };
__global__ __launch_bounds__(256)
void mega_kernel(PackSrc w, const void* mt, const void* at, const void* lt,
                 const float* __restrict__ posf, const int* __restrict__ flag,
                 unsigned short* __restrict__ Wqkvpk, unsigned short* __restrict__ Wopk,
                 unsigned short* __restrict__ W1pk, unsigned short* __restrict__ W2pk,
                 unsigned short* __restrict__ pe_b, float* __restrict__ out_f,
                 unsigned short* __restrict__ pk1, unsigned short* __restrict__ qkpk,
                 int* __restrict__ idx_out) {
  __shared__ float sx[TT], sy[TT];
  __shared__ unsigned long long cbuf[4][64];
  int bid = blockIdx.x;
  if (bid < 12288) {
    // ---- packW: source-linear enumeration -> coalesced reads, local scatter writes
    int f = *flag;
    int id = bid * 256 + threadIdx.x;
    if (id < 786432) {                  // Wq,Wk,Wv (K=256,N=256)
      int layer = id / 196608, rest = id % 196608;
      int sel = rest >> 16, e = rest & 65535;
      int k = e >> 8, col = e & 255;
      const void* src = w.s[sel];
      size_t si = (size_t)layer * 65536 + e;
      Wqkvpk[(size_t)layer * 196608 + (size_t)sel * 65536 + pk_addr(col, k, 8)] =
          f ? ((const unsigned short*)src)[si] : f2b(((const float*)src)[si]);
    } else if (id < 1048576) {          // Wo (K=256,N=256)
      int off = id - 786432, layer = off >> 16, e = off & 65535;
      int k = e >> 8, col = e & 255;
      size_t si = (size_t)layer * 65536 + e;
      Wopk[(size_t)layer * 65536 + pk_addr(col, k, 8)] =
          f ? ((const unsigned short*)w.s[3])[si] : f2b(((const float*)w.s[3])[si]);
    } else if (id < 2097152) {          // W1 (K=256,N=1024)
      int off = id - 1048576, layer = off >> 18, e = off & 262143;
      int k = e >> 10, col = e & 1023;
      size_t si = (size_t)layer * 262144 + e;
      W1pk[(size_t)layer * 262144 + pk_addr(col, k, 8)] =
          f ? ((const unsigned short*)w.s[4])[si] : f2b(((const float*)w.s[4])[si]);
    } else {                            // W2 (K=1024,N=256)
      int off = id - 2097152, layer = off >> 18, e = off & 262143;
      int k = e >> 8, col = e & 255;
      size_t si = (size_t)layer * 262144 + e;
      W2pk[(size_t)layer * 262144 + pk_addr(col, k, 32)] =
          f ? ((const unsigned short*)w.s[5])[si] : f2b(((const float*)w.s[5])[si]);
    }
    return;
  }
  if (bid < 19968) {
    // ---- prep: positional embedding + stream init
    // trig fast path: 10000^(-expo) via exp2f (HW v_exp), __sinf/__cosf (HW v_sin/v_cos).
    int n = swiz_tok(bid - 12288), d = threadIdx.x;
    int b = n / TT, t = n - b * TT;
    int f = *flag;
    const void* src; size_t si;
    if (t < MTOK)              { src = mt; si = (size_t)(b * MTOK + t) * DD + d; }
    else if (t < MTOK + NTOK)  { src = at; si = (size_t)(b * NTOK + (t - MTOK)) * DD + d; }
    else                       { src = lt; si = (size_t)(b * LTOK + (t - MTOK - NTOK)) * DD + d; }
    float x = load_elem(src, si, f);
    float px = posf[((size_t)b * TT + t) * 2 + 0];
    float py = posf[((size_t)b * TT + t) * 2 + 1];
    float coord = (d < 128) ? py : px;
    int j = d & 127;
    float expo = (float)(2 * (j >> 1)) / 128.0f;
    // 2*pi / 10000^expo = 2*pi * 2^(-expo*log2(10000))
    float fct = 6.283185307179586f * exp2f(expo * -13.287712379549449f);
    float e = coord * fct;
    float p = (j & 1) ? __cosf(e) : __sinf(e);
    size_t o = (size_t)n * DD + d;
    pe_b[o] = f2b(p);
    out_f[o] = x;
    size_t pa = pk_addr(n, d, 8);
    pk1[pa] = f2b(x);
    qkpk[pa] = f2b(x + p);
    return;
  }
  // ---- knn: threshold-prune + bitonic top-32 (exact)
  int kb = bid - 19968;
  int b = kb & 7;
  int qbase = (kb >> 3) * 4;
  for (int t = threadIdx.x; t < TT; t += 256) {
    sx[t] = posf[((size_t)b * TT + t) * 2 + 0];
    sy[t] = posf[((size_t)b * TT + t) * 2 + 1];
  }
  __syncthreads();
  int wave = threadIdx.x >> 6, lane = threadIdx.x & 63;
  int t = qbase + wave;
  float qx = sx[t], qy = sy[t];

  unsigned long long k[15];
#pragma unroll
  for (int c = 0; c < 15; c++) {
    int j = c * 64 + lane;
    float dx = qx - sx[j], dy = qy - sy[j];
    float d2 = __fadd_rn(__fmul_rn(dx, dx), __fmul_rn(dy, dy));
    k[c] = ((unsigned long long)__float_as_uint(d2) << 32) | (unsigned)j;
  }
  unsigned long long lm = k[0];
#pragma unroll
  for (int c = 1; c < 15; c++) lm = (k[c] < lm) ? k[c] : lm;

  unsigned long long sm = bitonic64(lm, lane);
  unsigned long long thr = shfl_u64(sm, 31);

  int c_l = 0;
#pragma unroll
  for (int c = 0; c < 15; c++) c_l += (k[c] <= thr) ? 1 : 0;
  int inc = c_l;
#pragma unroll
  for (int o = 1; o < 64; o <<= 1) {
    int tt = __shfl_up(inc, o);
    inc += (lane >= o) ? tt : 0;
  }
  int total = __shfl(inc, 63);
  int pos = inc - c_l;

  if (total <= 64) {
    unsigned long long* wb = cbuf[wave];
#pragma unroll
    for (int c = 0; c < 15; c++) {
      if (k[c] <= thr) { wb[pos] = k[c]; pos++; }
    }
    unsigned long long cand = (lane < total) ? wb[lane] : ~0ull;
    cand = bitonic64(cand, lane);
    if (lane < KNN)
      idx_out[((size_t)(b * TT + t)) * KNN + lane] = b * TT + (int)(cand & 0xFFFFFFFFu);
  } else {
    unsigned res = 0;
    for (int i = 0; i < KNN; i++) {
      unsigned long long m = k[0];
#pragma unroll
      for (int c = 1; c < 15; c++) m = (k[c] < m) ? k[c] : m;
#pragma unroll
      for (int o = 32; o > 0; o >>= 1) {
        unsigned long long om = shfl_xor_u64(m, o);
        m = (om < m) ? om : m;
      }
      if (lane == i) res = (unsigned)(m & 0xFFFFFFFFu);
      int owner = (int)(m & 63u), ch = (int)(((unsigned)(m & 0xFFFFFFFFu)) >> 6);
      if (lane == owner) {
#pragma unroll
        for (int c = 0; c < 15; c++) if (c == ch) k[c] = ~0ull;
      }
    }
    if (lane < KNN)
      idx_out[((size_t)(b * TT + t)) * KNN + lane] = b * TT + (int)res;
  }
}

// ---------------- wave GEMM: 16 rows x NT*16 cols ----------------
template<int NKS, int NT>
__device__ __forceinline__ void wavegemm(const unsigned short* __restrict__ Apk,
                                         const unsigned short* __restrict__ Bpk,
                                         int rb, int cb0, accfrag_t (&acc)[NT]) {
  const int lane = threadIdx.x & 63;
  accfrag_t z = {0.f, 0.f, 0.f, 0.f};
#pragma unroll
  for (int nt = 0; nt < NT; nt++) acc[nt] = z;
  const unsigned short* ap = Apk + ((size_t)rb * NKS * 512 + lane * 8);
  const unsigned short* bp = Bpk + ((size_t)cb0 * NKS * 512 + lane * 8);
#pragma unroll 4
  for (int ks = 0; ks < NKS; ks++) {
    bfrag_t a = *(const bfrag_t*)(ap + ks * 512);
#pragma unroll
    for (int nt = 0; nt < NT; nt++) {
      bfrag_t b = *(const bfrag_t*)(bp + (size_t)(nt * NKS + ks) * 512);
      acc[nt] = __builtin_amdgcn_mfma_f32_16x16x32_bf16(a, b, acc[nt], 0, 0, 0);
    }
  }
}

// ---------------- QKV GEMM (layer 0 only): grid 1440 ----------------
__global__ __launch_bounds__(256)
void qkv_kernel(const unsigned short* __restrict__ qkpk,
                const unsigned short* __restrict__ outpk,
                const unsigned short* __restrict__ Wl,
                const float* __restrict__ pb, int l,
                unsigned short* __restrict__ QKV) {
  int scene = blockIdx.x & 7, r = blockIdx.x >> 3;
  int rbg = r % 15, cgall = r / 15;           // cgall 0..11
  int wave = threadIdx.x >> 6, lane = threadIdx.x & 63;
  int rb = scene * 60 + rbg * 4 + wave;
  int sel = cgall >> 2, cg = cgall & 3;
  const unsigned short* A = (sel < 2) ? qkpk : outpk;
  const unsigned short* B = Wl + sel * 65536;
  const float* bias = pb + sel * 1024 + l * 256;
  accfrag_t acc[4];
  wavegemm<8,4>(A, B, rb, cg * 4, acc);
  int l16 = lane & 15, lq = lane >> 4;
  unsigned short* C = QKV + (size_t)sel * BT * DD;
#pragma unroll
  for (int nt = 0; nt < 4; nt++) {
    int col = cg * 64 + nt * 16 + l16;
    float bv = bias[col];
#pragma unroll
    for (int r4 = 0; r4 < 4; r4++) {
      int row = rb * 16 + lq * 4 + r4;
      C[(size_t)row * DD + col] = f2b(acc[nt][r4] + bv);
    }
  }
}

// ---------------- attention (packed output; V read direct from L2, no staging) ----------------
__global__ __launch_bounds__(256)
void attn_kernel(const unsigned short* __restrict__ QKV,
                 const int* __restrict__ idx,
                 unsigned short* __restrict__ attnpk) {
  __shared__ unsigned short kn[KNN][DD + 8];
  __shared__ float qs[DD];
  __shared__ float att[HH][KNN];
  __shared__ int nb[KNN];
  const unsigned short* Q = QKV;
  const unsigned short* K = QKV + (size_t)BT * DD;
  const unsigned short* V = QKV + 2 * (size_t)BT * DD;
  int n = swiz_tok(blockIdx.x), tid = threadIdx.x;
  if (tid < KNN) nb[tid] = idx[n * KNN + tid];
  qs[tid] = b2f(Q[(size_t)n * DD + tid]);
  __syncthreads();
#pragma unroll
  for (int p = 0; p < 4; p++) {
    int e = p * 256 + tid;
    int r = e >> 6, c8 = (e & 63) * 4;      // 16 rows/pass x 64 chunks of 4 shorts? no:
    // keep original mapping but K only: e in [0,1024), r=e>>5 (0..31), c8=(e&31)*8
    r = e >> 5; c8 = (e & 31) * 8;
    int srow = nb[r];
    *(uint4*)(&kn[r][c8]) = *(const uint4*)(K + (size_t)srow * DD + c8);
  }
  __syncthreads();
  int h = tid >> 5, kk = tid & 31;
  float dot = 0.0f;
#pragma unroll
  for (int d = 0; d < HD; d++) dot += qs[h * HD + d] * b2f(kn[kk][h * HD + d]);
  float sc = dot * SCALE_ATT;
  float mx = sc;
#pragma unroll
  for (int o = 16; o > 0; o >>= 1) mx = fmaxf(mx, __shfl_xor(mx, o, 32));
  float ex = expf(sc - mx);
  float sm = ex;
#pragma unroll
  for (int o = 16; o > 0; o >>= 1) sm += __shfl_xor(sm, o, 32);
  att[h][kk] = ex / sm;
  __syncthreads();
  int d = kk;
  const unsigned short* Vh = V + h * HD + d;
  float oacc = 0.0f;
#pragma unroll
  for (int k2 = 0; k2 < KNN; k2++)
    oacc += att[h][k2] * b2f(Vh[(size_t)nb[k2] * DD]);
  attnpk[pk_addr(n, tid, 8)] = f2b(oacc);
}

// ---------------- fused block: Wo+resid+LN1 -> FFN1 -> FFN2+resid+LN2 [-> next QKV] ----------------
// R8-proven structure: grid 480 x 256 threads (4 waves). One block = one 16-row block.
template<bool LAST>
__global__ __launch_bounds__(256)
void ffn_block_kernel(const unsigned short* __restrict__ attnpk,
                      const unsigned short* __restrict__ Wo,
                      const unsigned short* __restrict__ W1,
                      const unsigned short* __restrict__ W2,
                      const unsigned short* __restrict__ Wn,   // next-layer Wqkv (packed)
                      const float* __restrict__ bo,
                      const float* __restrict__ b1,
                      const float* __restrict__ b2,
                      const float* __restrict__ pb, int ln,    // bias base, next layer idx
                      float* __restrict__ yf,                  // residual stream (f32)
                      const unsigned short* __restrict__ pe_b,
                      const float* __restrict__ g1, const float* __restrict__ t1,
                      const float* __restrict__ g2, const float* __restrict__ t2,
                      unsigned short* __restrict__ QKV,
                      void* __restrict__ dout, const int* __restrict__ flag) {
  __shared__ unsigned short xls[8 * 512];    // 16r x 256k packed (NKS=8), 8 KB
  __shared__ unsigned short hls[32 * 512];   // 16r x 1024k packed (NKS=32), 32 KB
  __shared__ float ps1[4][16], ps2[4][16];
  int scene = blockIdx.x & 7, rbs = blockIdx.x >> 3;   // rbs 0..59
  int wave = threadIdx.x >> 6, lane = threadIdx.x & 63;
  int rb = scene * 60 + rbs;
  int l16 = lane & 15, lq = lane >> 4;

  // ---- residual prefetch (issue loads before the GEMM; consumed in LN1 epilogue)
  float resv[4][4];
#pragma unroll
  for (int nt = 0; nt < 4; nt++) {
    int col = wave * 64 + nt * 16 + l16;
#pragma unroll
    for (int r4 = 0; r4 < 4; r4++) {
      int row = rb * 16 + lq * 4 + r4;
      resv[nt][r4] = yf[(size_t)row * DD + col];
    }
  }

  // ---- phase 1: Wo GEMM + bias + residual + LN1 -> y (regs) + xls (LDS packed)
  accfrag_t acc[4];
  wavegemm<8,4>(attnpk, Wo, rb, wave * 4, acc);
  float y[4][4];
  float s[4] = {0.f, 0.f, 0.f, 0.f}, s2[4] = {0.f, 0.f, 0.f, 0.f};
#pragma unroll
  for (int nt = 0; nt < 4; nt++) {
    int col = wave * 64 + nt * 16 + l16;
    float bv = bo[col];
#pragma unroll
    for (int r4 = 0; r4 < 4; r4++) {
      float x = acc[nt][r4] + bv + resv[nt][r4];
      y[nt][r4] = x; s[r4] += x; s2[r4] += x * x;
    }
  }
#pragma unroll
  for (int o = 1; o < 16; o <<= 1) {
#pragma unroll
    for (int r4 = 0; r4 < 4; r4++) { s[r4] += __shfl_xor(s[r4], o); s2[r4] += __shfl_xor(s2[r4], o); }
  }
  if (l16 == 0) {
#pragma unroll
    for (int r4 = 0; r4 < 4; r4++) { ps1[wave][lq * 4 + r4] = s[r4]; ps2[wave][lq * 4 + r4] = s2[r4]; }
  }
  __syncthreads();
#pragma unroll
  for (int r4 = 0; r4 < 4; r4++) {
    int r16 = lq * 4 + r4;
    float ts  = ps1[0][r16] + ps1[1][r16] + ps1[2][r16] + ps1[3][r16];
    float ts2 = ps2[0][r16] + ps2[1][r16] + ps2[2][r16] + ps2[3][r16];
    float mu = ts * (1.0f / 256.0f);
    float var = ts2 * (1.0f / 256.0f) - mu * mu;
    float rstd = 1.0f / sqrtf(fmaxf(var, 0.f) + 1e-5f);
#pragma unroll
    for (int nt = 0; nt < 4; nt++) {
      int col = wave * 64 + nt * 16 + l16;
      float v = (y[nt][r4] - mu) * rstd * g1[col] + t1[col];
      y[nt][r4] = v;
      xls[pk_addr(r16, col, 8)] = f2b(v);
    }
  }
  __syncthreads();

  // ---- phase 2: FFN1 (xls @ W1 + b1, ReLU) -> hls (LDS packed)
#pragma unroll
  for (int i = 0; i < 4; i++) {
    int cg = wave * 4 + i;
    accfrag_t a2[4];
    wavegemm<8,4>(xls, W1, 0, cg * 4, a2);
#pragma unroll
    for (int nt = 0; nt < 4; nt++) {
      int col = cg * 64 + nt * 16 + l16;
      float bv = b1[col];
#pragma unroll
      for (int r4 = 0; r4 < 4; r4++)
        hls[pk_addr(lq * 4 + r4, col, 32)] = f2b(fmaxf(a2[nt][r4] + bv, 0.0f));
    }
  }
  __syncthreads();

  // ---- phase 3: FFN2 (hls @ W2 + b2) + residual(y) + LN2
  accfrag_t a3[4];
  wavegemm<32,4>(hls, W2, 0, wave * 4, a3);
  float v2[4][4];
  float s3[4] = {0.f, 0.f, 0.f, 0.f}, s4[4] = {0.f, 0.f, 0.f, 0.f};
#pragma unroll
  for (int nt = 0; nt < 4; nt++) {
    int col = wave * 64 + nt * 16 + l16;
    float bv = b2[col];
#pragma unroll
    for (int r4 = 0; r4 < 4; r4++) {
      float x = a3[nt][r4] + bv + y[nt][r4];
      v2[nt][r4] = x; s3[r4] += x; s4[r4] += x * x;
    }
  }
#pragma unroll
  for (int o = 1; o < 16; o <<= 1) {
#pragma unroll
    for (int r4 = 0; r4 < 4; r4++) { s3[r4] += __shfl_xor(s3[r4], o); s4[r4] += __shfl_xor(s4[r4], o); }
  }
  if (l16 == 0) {
#pragma unroll
    for (int r4 = 0; r4 < 4; r4++) { ps1[wave][lq * 4 + r4] = s3[r4]; ps2[wave][lq * 4 + r4] = s4[r4]; }
  }
  __syncthreads();     // after this barrier all waves are done reading hls (phase-3 GEMM)
  unsigned short* qkls = hls;   // reuse first 8 KB of hls for packed (y+pe)
  int fl = LAST ? *flag : 0;
#pragma unroll
  for (int r4 = 0; r4 < 4; r4++) {
    int r16 = lq * 4 + r4;
    float ts  = ps1[0][r16] + ps1[1][r16] + ps1[2][r16] + ps1[3][r16];
    float ts2 = ps2[0][r16] + ps2[1][r16] + ps2[2][r16] + ps2[3][r16];
    float mu = ts * (1.0f / 256.0f);
    float var = ts2 * (1.0f / 256.0f) - mu * mu;
    float rstd = 1.0f / sqrtf(fmaxf(var, 0.f) + 1e-5f);
#pragma unroll
    for (int nt = 0; nt < 4; nt++) {
      int col = wave * 64 + nt * 16 + l16;
      float yv = (v2[nt][r4] - mu) * rstd * g2[col] + t2[col];
      int row = rb * 16 + r16;
      if (!LAST) {
        yf[(size_t)row * DD + col] = yv;           // residual for next layer
        float q = yv + b2f(pe_b[(size_t)row * DD + col]);
        xls[pk_addr(r16, col, 8)] = f2b(yv);       // out (for V projection)
        qkls[pk_addr(r16, col, 8)] = f2b(q);       // out+pe (for Q/K projection)
      } else {
        int t = rbs * 16 + r16;   // token within scene
        size_t o;
        if (t < MTOK)             o = (size_t)(scene * MTOK + t) * DD + col;
        else if (t < MTOK + NTOK) o = (size_t)BB * MTOK * DD + (size_t)(scene * NTOK + (t - MTOK)) * DD + col;
        else                      o = (size_t)BB * MTOK * DD + (size_t)BB * NTOK * DD
                                    + (size_t)(scene * LTOK + (t - MTOK - NTOK)) * DD + col;
        if (fl) ((unsigned short*)dout)[o] = f2b(yv);
        else    ((float*)dout)[o] = yv;
      }
    }
  }

  // ---- phase 4 (!LAST): next-layer QKV projection straight from LDS
  if (!LAST) {
    __syncthreads();
#pragma unroll
    for (int i = 0; i < 3; i++) {
      int cgall = wave * 3 + i;            // 12 tiles: Q(0-3) K(4-7) V(8-11)
      int sel = cgall >> 2, cg = cgall & 3;
      const unsigned short* A = (sel < 2) ? qkls : xls;
      accfrag_t a4[4];
      wavegemm<8,4>(A, Wn + sel * 65536, 0, cg * 4, a4);
      const float* bias = pb + sel * 1024 + ln * 256;
      unsigned short* C = QKV + (size_t)sel * BT * DD;
#pragma unroll
      for (int nt = 0; nt < 4; nt++) {
        int col = cg * 64 + nt * 16 + l16;
        float bv = bias[col];
#pragma unroll
        for (int r4 = 0; r4 < 4; r4++) {
          int row = rb * 16 + lq * 4 + r4;
          C[(size_t)row * DD + col] = f2b(a4[nt][r4] + bv);
        }
      }
    }
  }
}

// ---------------- launcher ----------------
extern "C" void kernel_launch(void* const* d_in, const int* in_sizes, int n_in,
                              void* d_out, int out_size, void* d_ws, size_t ws_size,
                              hipStream_t stream) {
  const void* map_tok   = d_in[0];
  const void* agent_tok = d_in[1];
  const void* light_tok = d_in[2];
  const void* map_pos   = d_in[3];
  const void* agent_pos = d_in[4];
  const void* light_pos = d_in[5];
  const void* Wq  = d_in[9];
  const void* bq  = d_in[10];
  const void* Wk  = d_in[11];
  const void* bk  = d_in[12];
  const void* Wv  = d_in[13];
  const void* bv  = d_in[14];
  const void* Wo  = d_in[15];
  const void* bo  = d_in[16];
  const void* W1  = d_in[17];
  const void* b1  = d_in[18];
  const void* W2  = d_in[19];
  const void* b2  = d_in[20];
  const void* ln1s = d_in[21];
  const void* ln1b = d_in[22];
  const void* ln2s = d_in[23];
  const void* ln2b = d_in[24];

  size_t off = 0;
  char* base = (char*)d_ws;
  auto take = [&](size_t bytes) { char* p = base + off; off += (bytes + 255) & ~(size_t)255; return (void*)p; };
  int*   flag  = (int*)take(256);
  float* posf  = (float*)take((size_t)BT * 2 * 4);
  float* pbuf  = (float*)take((size_t)FB_TOTAL * 4);
  unsigned short* pe_b = (unsigned short*)take((size_t)BT * DD * 2);
  float* out_f = (float*)take((size_t)BT * DD * 4);   // residual stream (f32)
  unsigned short* pk1  = (unsigned short*)take((size_t)BT * DD * 2);  // layer-0 x packed
  unsigned short* qkpk = (unsigned short*)take((size_t)BT * DD * 2);  // layer-0 x+pe packed
  unsigned short* QKV  = (unsigned short*)take((size_t)3 * BT * DD * 2);
  unsigned short* attnpk = (unsigned short*)take((size_t)BT * DD * 2);
  int* idxb = (int*)take((size_t)BT * KNN * 4);
  unsigned short* Wqkvpk = (unsigned short*)take((size_t)NLAYERS * 3 * DD * DD * 2);
  unsigned short* Wopk   = (unsigned short*)take((size_t)NLAYERS * DD * DD * 2);
  unsigned short* W1pk   = (unsigned short*)take((size_t)NLAYERS * DD * FFD * 2);
  unsigned short* W2pk   = (unsigned short*)take((size_t)NLAYERS * DD * FFD * 2);

  ParamSrc ps; ps.p[0]=bq; ps.p[1]=bk; ps.p[2]=bv; ps.p[3]=bo; ps.p[4]=b1;
  ps.p[5]=b2; ps.p[6]=ln1s; ps.p[7]=ln1b; ps.p[8]=ln2s; ps.p[9]=ln2b;
  ps.p[10]=map_pos; ps.p[11]=agent_pos; ps.p[12]=light_pos;
  conv_misc_kernel<<<BB + (FB_TOTAL + 255) / 256, 256, 0, stream>>>(ps, map_tok, flag, pbuf, posf);

  PackSrc pw; pw.s[0]=Wq; pw.s[1]=Wk; pw.s[2]=Wv; pw.s[3]=Wo; pw.s[4]=W1; pw.s[5]=W2;
  mega_kernel<<<21888, 256, 0, stream>>>(pw, map_tok, agent_tok, light_tok, posf, flag,
                                         Wqkvpk, Wopk, W1pk, W2pk,
                                         pe_b, out_f, pk1, qkpk, idxb);

  qkv_kernel<<<1440, 256, 0, stream>>>(qkpk, pk1, Wqkvpk, pbuf, 0, QKV);

  for (int l = 0; l < NLAYERS; l++) {
    attn_kernel<<<BT, 256, 0, stream>>>(QKV, idxb, attnpk);
    if (l < NLAYERS - 1)
      ffn_block_kernel<false><<<480, 256, 0, stream>>>(
          attnpk, Wopk + (size_t)l * 65536, W1pk + (size_t)l * 262144, W2pk + (size_t)l * 262144,
          Wqkvpk + (size_t)(l + 1) * 196608,
          pbuf + FB_BO + l * 256, pbuf + FB_B1 + l * 1024, pbuf + FB_B2 + l * 256,
          pbuf, l + 1,
          out_f, pe_b,
          pbuf + FB_LN1S + l * 256, pbuf + FB_LN1B + l * 256,
          pbuf + FB_LN2S + l * 256, pbuf + FB_LN2B + l * 256,
          QKV, d_out, flag);
    else
      ffn_block_kernel<true><<<480, 256, 0, stream>>>(
          attnpk, Wopk + (size_t)l * 65536, W1pk + (size_t)l * 262144, W2pk + (size_t)l * 262144,
          Wqkvpk,
          pbuf + FB_BO + l * 256, pbuf + FB_B1 + l * 1024, pbuf + FB_B2 + l * 256,
          pbuf, 0,
          out_f, pe_b,
          pbuf + FB_LN1S + l * 256, pbuf + FB_LN1B + l * 256,
          pbuf + FB_LN2S + l * 256, pbuf + FB_LN2B + l * 256,
          QKV, d_out, flag);
  }
}